// Round 1
// baseline (2534.767 us; speedup 1.0000x reference)
//
#include <hip/hip_runtime.h>

#define N_NODES 50000
#define E_EDGES 800000
#define DIN 256
#define H 128
#define DOUT 64
#define EPSF 1e-5f

// ---------------- in_proj: h = x @ W_in + b_in ----------------
// 256 threads, 8 nodes/block. tx = col (128), ty = 0..1 -> 4 nodes each.
__global__ __launch_bounds__(256) void k_in_proj(const float* __restrict__ x,
                                                 const float* __restrict__ W,   // 256x128
                                                 const float* __restrict__ b,   // 128
                                                 float* __restrict__ h)
{
    __shared__ float xs[8 * DIN]; // 8 KiB
    int tid = threadIdx.x;
    int n0 = blockIdx.x * 8;
    const float4* xsrc = (const float4*)(x + (size_t)n0 * DIN);
    float4* xd = (float4*)xs;
    xd[tid] = xsrc[tid];
    xd[tid + 256] = xsrc[tid + 256];
    __syncthreads();

    int tx = tid & 127;
    int ty = tid >> 7;
    float a0 = 0.f, a1 = 0.f, a2 = 0.f, a3 = 0.f;
    const float* xr = xs + ty * 4 * DIN;
    #pragma unroll 4
    for (int k = 0; k < DIN; ++k) {
        float w = W[k * H + tx];
        a0 = fmaf(xr[k          ], w, a0);
        a1 = fmaf(xr[k +     DIN], w, a1);
        a2 = fmaf(xr[k + 2 * DIN], w, a2);
        a3 = fmaf(xr[k + 3 * DIN], w, a3);
    }
    float bias = b[tx];
    int nb = n0 + ty * 4;
    h[(size_t)(nb + 0) * H + tx] = a0 + bias;
    h[(size_t)(nb + 1) * H + tx] = a1 + bias;
    h[(size_t)(nb + 2) * H + tx] = a2 + bias;
    h[(size_t)(nb + 3) * H + tx] = a3 + bias;
}

// ------------- fused k,q,v,self GEMMs for one layer -------------
// agg is fully (re)written here = h @ Ws + b_gcn (no memset needed).
__global__ __launch_bounds__(256) void k_qkvs(const float* __restrict__ h,
                                              const float* __restrict__ Wk, const float* __restrict__ bk,
                                              const float* __restrict__ Wq, const float* __restrict__ bq,
                                              const float* __restrict__ Wv, const float* __restrict__ bv,
                                              const float* __restrict__ Ws, const float* __restrict__ bs,
                                              float* __restrict__ ko, float* __restrict__ qo,
                                              float* __restrict__ vo, float* __restrict__ agg)
{
    __shared__ float hs[8 * H]; // 4 KiB
    int tid = threadIdx.x;
    int n0 = blockIdx.x * 8;
    ((float4*)hs)[tid] = ((const float4*)(h + (size_t)n0 * H))[tid];
    __syncthreads();

    int tx = tid & 127;
    int ty = tid >> 7;
    float ak[4] = {0,0,0,0}, aq[4] = {0,0,0,0}, av[4] = {0,0,0,0}, as[4] = {0,0,0,0};
    const float* hr = hs + ty * 4 * H;
    #pragma unroll 2
    for (int k = 0; k < H; ++k) {
        float wk = Wk[k * H + tx];
        float wq = Wq[k * H + tx];
        float wv = Wv[k * H + tx];
        float ws = Ws[k * H + tx];
        #pragma unroll
        for (int n = 0; n < 4; ++n) {
            float xv = hr[n * H + k];
            ak[n] = fmaf(xv, wk, ak[n]);
            aq[n] = fmaf(xv, wq, aq[n]);
            av[n] = fmaf(xv, wv, av[n]);
            as[n] = fmaf(xv, ws, as[n]);
        }
    }
    float bbk = bk[tx], bbq = bq[tx], bbv = bv[tx], bbs = bs[tx];
    #pragma unroll
    for (int n = 0; n < 4; ++n) {
        size_t idx = (size_t)(n0 + ty * 4 + n) * H + tx;
        ko[idx]  = ak[n] + bbk;
        qo[idx]  = aq[n] + bbq;
        vo[idx]  = av[n] + bbv;
        agg[idx] = as[n] + bbs;
    }
}

// ------------- edge kernel: gate + message + scatter-add -------------
// one wave (64 lanes) per edge, float2 per lane over 128 features.
__global__ __launch_bounds__(256) void k_edge(const int* __restrict__ ei,   // 2 x E
                                              const float* __restrict__ ea, // E
                                              const float* __restrict__ ko,
                                              const float* __restrict__ qo,
                                              const float* __restrict__ vo,
                                              const float* __restrict__ We, // 128
                                              const float* __restrict__ be, // 128
                                              float* __restrict__ agg)
{
    int tid = threadIdx.x;
    int lane = tid & 63;
    int eid = blockIdx.x * 4 + (tid >> 6);
    int src = ei[eid];
    int dst = ei[E_EDGES + eid];
    float a = ea[eid];
    int j = lane * 2;
    float2 we  = *(const float2*)(We + j);
    float2 bev = *(const float2*)(be + j);
    float2 kd  = *(const float2*)(ko + (size_t)dst * H + j);
    float2 qs  = *(const float2*)(qo + (size_t)src * H + j);
    float2 vs  = *(const float2*)(vo + (size_t)src * H + j);
    float e0 = fmaf(a, we.x, bev.x);
    float e1 = fmaf(a, we.y, bev.y);
    float g0 = kd.x + qs.x + 2.f * e0;
    float g1 = kd.y + qs.y + 2.f * e1;
    g0 = 1.f / (1.f + __expf(-g0));
    g1 = 1.f / (1.f + __expf(-g1));
    float m0 = g0 * (vs.x + e0);
    float m1 = g1 * (vs.y + e1);
    float* dp = agg + (size_t)dst * H + j;
    atomicAdd(dp, m0);
    atomicAdd(dp + 1, m1);
}

// ------------- LayerNorm + exact GELU, one wave per node -------------
__global__ __launch_bounds__(256) void k_ln_gelu(const float* __restrict__ agg,
                                                 const float* __restrict__ gamma,
                                                 const float* __restrict__ beta,
                                                 float* __restrict__ h)
{
    int tid = threadIdx.x;
    int lane = tid & 63;
    int node = blockIdx.x * 4 + (tid >> 6);
    float2 v = *(const float2*)(agg + (size_t)node * H + lane * 2);
    float s  = v.x + v.y;
    float s2 = v.x * v.x + v.y * v.y;
    #pragma unroll
    for (int off = 32; off > 0; off >>= 1) {
        s  += __shfl_down(s, off);
        s2 += __shfl_down(s2, off);
    }
    s  = __shfl(s, 0);
    s2 = __shfl(s2, 0);
    float mu  = s * (1.f / H);
    float var = s2 * (1.f / H) - mu * mu;
    float rstd = rsqrtf(var + EPSF);
    float2 g = *(const float2*)(gamma + lane * 2);
    float2 b = *(const float2*)(beta + lane * 2);
    float y0 = (v.x - mu) * rstd * g.x + b.x;
    float y1 = (v.y - mu) * rstd * g.y + b.y;
    y0 = 0.5f * y0 * (1.f + erff(y0 * 0.70710678118f));
    y1 = 0.5f * y1 * (1.f + erff(y1 * 0.70710678118f));
    *(float2*)(h + (size_t)node * H + lane * 2) = make_float2(y0, y1);
}

// ------------- out_proj: out = h @ W_out -------------
__global__ __launch_bounds__(256) void k_out(const float* __restrict__ h,
                                             const float* __restrict__ W, // 128x64
                                             float* __restrict__ out)
{
    __shared__ float hs[8 * H];
    int tid = threadIdx.x;
    int n0 = blockIdx.x * 8;
    ((float4*)hs)[tid] = ((const float4*)(h + (size_t)n0 * H))[tid];
    __syncthreads();
    int tx = tid & 63;
    int ty = tid >> 6; // 0..3, 2 nodes each
    float a0 = 0.f, a1 = 0.f;
    const float* hr = hs + ty * 2 * H;
    #pragma unroll 4
    for (int k = 0; k < H; ++k) {
        float w = W[k * DOUT + tx];
        a0 = fmaf(hr[k    ], w, a0);
        a1 = fmaf(hr[k + H], w, a1);
    }
    int nb = n0 + ty * 2;
    out[(size_t)(nb + 0) * DOUT + tx] = a0;
    out[(size_t)(nb + 1) * DOUT + tx] = a1;
}

extern "C" void kernel_launch(void* const* d_in, const int* in_sizes, int n_in,
                              void* d_out, int out_size, void* d_ws, size_t ws_size,
                              hipStream_t stream) {
    const float* x         = (const float*)d_in[0];
    const float* edge_attr = (const float*)d_in[1];
    const float* W_in      = (const float*)d_in[2];
    const float* b_in      = (const float*)d_in[3];
    const float* Wk        = (const float*)d_in[4];
    const float* bk        = (const float*)d_in[5];
    const float* Wq        = (const float*)d_in[6];
    const float* bq        = (const float*)d_in[7];
    const float* Wv        = (const float*)d_in[8];
    const float* bv        = (const float*)d_in[9];
    const float* We        = (const float*)d_in[10];
    const float* be        = (const float*)d_in[11];
    const float* Ws        = (const float*)d_in[12];
    const float* b_gcn     = (const float*)d_in[13];
    const float* gamma     = (const float*)d_in[14];
    const float* beta      = (const float*)d_in[15];
    const float* W_out     = (const float*)d_in[16];
    const int*   edge_index= (const int*)d_in[17];
    float* out = (float*)d_out;

    float* ws  = (float*)d_ws;
    float* h   = ws;                          // N*H
    float* ko  = h  + (size_t)N_NODES * H;    // N*H
    float* qo  = ko + (size_t)N_NODES * H;    // N*H
    float* vo  = qo + (size_t)N_NODES * H;    // N*H
    float* agg = vo + (size_t)N_NODES * H;    // N*H

    k_in_proj<<<N_NODES / 8, 256, 0, stream>>>(x, W_in, b_in, h);
    for (int l = 0; l < 3; ++l) {
        k_qkvs<<<N_NODES / 8, 256, 0, stream>>>(h,
            Wk + (size_t)l * H * H, bk + l * H,
            Wq + (size_t)l * H * H, bq + l * H,
            Wv + (size_t)l * H * H, bv + l * H,
            Ws + (size_t)l * H * H, b_gcn + l * H,
            ko, qo, vo, agg);
        k_edge<<<E_EDGES / 4, 256, 0, stream>>>(edge_index, edge_attr, ko, qo, vo,
                                                We + l * H, be + l * H, agg);
        k_ln_gelu<<<N_NODES / 4, 256, 0, stream>>>(agg, gamma + l * H, beta + l * H, h);
    }
    k_out<<<N_NODES / 8, 256, 0, stream>>>(h, W_out, out);
}

// Round 2
// 1028.722 us; speedup vs baseline: 2.4640x; 2.4640x over previous
//
#include <hip/hip_runtime.h>

#define N_NODES 50000
#define E_EDGES 800000
#define DIN 256
#define H 128
#define DOUT 64
#define EPSF 1e-5f

// ---------------- in_proj: h = x @ W_in + b_in ----------------
__global__ __launch_bounds__(256) void k_in_proj(const float* __restrict__ x,
                                                 const float* __restrict__ W,   // 256x128
                                                 const float* __restrict__ b,   // 128
                                                 float* __restrict__ h)
{
    __shared__ float xs[8 * DIN]; // 8 KiB
    int tid = threadIdx.x;
    int n0 = blockIdx.x * 8;
    const float4* xsrc = (const float4*)(x + (size_t)n0 * DIN);
    float4* xd = (float4*)xs;
    xd[tid] = xsrc[tid];
    xd[tid + 256] = xsrc[tid + 256];
    __syncthreads();

    int tx = tid & 127;
    int ty = tid >> 7;
    float a0 = 0.f, a1 = 0.f, a2 = 0.f, a3 = 0.f;
    const float* xr = xs + ty * 4 * DIN;
    #pragma unroll 4
    for (int k = 0; k < DIN; ++k) {
        float w = W[k * H + tx];
        a0 = fmaf(xr[k          ], w, a0);
        a1 = fmaf(xr[k +     DIN], w, a1);
        a2 = fmaf(xr[k + 2 * DIN], w, a2);
        a3 = fmaf(xr[k + 3 * DIN], w, a3);
    }
    float bias = b[tx];
    int nb = n0 + ty * 4;
    h[(size_t)(nb + 0) * H + tx] = a0 + bias;
    h[(size_t)(nb + 1) * H + tx] = a1 + bias;
    h[(size_t)(nb + 2) * H + tx] = a2 + bias;
    h[(size_t)(nb + 3) * H + tx] = a3 + bias;
}

// ------------- fused k,q,v,self GEMMs for one layer -------------
__global__ __launch_bounds__(256) void k_qkvs(const float* __restrict__ h,
                                              const float* __restrict__ Wk, const float* __restrict__ bk,
                                              const float* __restrict__ Wq, const float* __restrict__ bq,
                                              const float* __restrict__ Wv, const float* __restrict__ bv,
                                              const float* __restrict__ Ws, const float* __restrict__ bs,
                                              float* __restrict__ ko, float* __restrict__ qo,
                                              float* __restrict__ vo, float* __restrict__ agg)
{
    __shared__ float hs[8 * H]; // 4 KiB
    int tid = threadIdx.x;
    int n0 = blockIdx.x * 8;
    ((float4*)hs)[tid] = ((const float4*)(h + (size_t)n0 * H))[tid];
    __syncthreads();

    int tx = tid & 127;
    int ty = tid >> 7;
    float ak[4] = {0,0,0,0}, aq[4] = {0,0,0,0}, av[4] = {0,0,0,0}, as[4] = {0,0,0,0};
    const float* hr = hs + ty * 4 * H;
    #pragma unroll 2
    for (int k = 0; k < H; ++k) {
        float wk = Wk[k * H + tx];
        float wq = Wq[k * H + tx];
        float wv = Wv[k * H + tx];
        float ws = Ws[k * H + tx];
        #pragma unroll
        for (int n = 0; n < 4; ++n) {
            float xv = hr[n * H + k];
            ak[n] = fmaf(xv, wk, ak[n]);
            aq[n] = fmaf(xv, wq, aq[n]);
            av[n] = fmaf(xv, wv, av[n]);
            as[n] = fmaf(xv, ws, as[n]);
        }
    }
    float bbk = bk[tx], bbq = bq[tx], bbv = bv[tx], bbs = bs[tx];
    #pragma unroll
    for (int n = 0; n < 4; ++n) {
        size_t idx = (size_t)(n0 + ty * 4 + n) * H + tx;
        ko[idx]  = ak[n] + bbk;
        qo[idx]  = aq[n] + bbq;
        vo[idx]  = av[n] + bbv;
        agg[idx] = as[n] + bbs;
    }
}

// ================= CSR build (once per launch) =================
__global__ __launch_bounds__(256) void k_zero(int* __restrict__ deg, int* __restrict__ fill)
{
    int i = blockIdx.x * 256 + threadIdx.x;
    if (i < N_NODES) { deg[i] = 0; fill[i] = 0; }
}

__global__ __launch_bounds__(256) void k_hist(const int* __restrict__ ei, int* __restrict__ deg)
{
    int e = blockIdx.x * 256 + threadIdx.x;
    int dst = ei[E_EDGES + e];
    atomicAdd(&deg[dst], 1);
}

// single-block exclusive scan of deg[0..N) -> rowptr[0..N]
__global__ __launch_bounds__(1024) void k_scan(const int* __restrict__ deg, int* __restrict__ rowptr)
{
    __shared__ int wsum[16];
    int tid = threadIdx.x;
    const int CH = (N_NODES + 1023) / 1024; // 49
    int beg = tid * CH;
    int end = beg + CH; if (end > N_NODES) end = N_NODES; if (beg > N_NODES) beg = N_NODES;
    int local = 0;
    for (int i = beg; i < end; ++i) local += deg[i];
    int lane = tid & 63, wid = tid >> 6;
    int v = local;
    #pragma unroll
    for (int off = 1; off < 64; off <<= 1) {
        int t = __shfl_up(v, off);
        if (lane >= off) v += t;
    }
    if (lane == 63) wsum[wid] = v;
    __syncthreads();
    if (wid == 0 && lane < 16) {
        int s = wsum[lane];
        #pragma unroll
        for (int off = 1; off < 16; off <<= 1) {
            int t = __shfl_up(s, off);
            if (lane >= off) s += t;
        }
        wsum[lane] = s;
    }
    __syncthreads();
    int waveoff = (wid > 0) ? wsum[wid - 1] : 0;
    int run = v - local + waveoff; // exclusive prefix of this thread's chunk
    for (int i = beg; i < end; ++i) { rowptr[i] = run; run += deg[i]; }
    if (tid == 1023) rowptr[N_NODES] = run;
}

__global__ __launch_bounds__(256) void k_scatter(const int* __restrict__ ei,
                                                 const float* __restrict__ ea,
                                                 const int* __restrict__ rowptr,
                                                 int* __restrict__ fill,
                                                 int* __restrict__ csr_src,
                                                 float* __restrict__ csr_ea)
{
    int e = blockIdx.x * 256 + threadIdx.x;
    int src = ei[e];
    int dst = ei[E_EDGES + e];
    int pos = rowptr[dst] + atomicAdd(&fill[dst], 1);
    csr_src[pos] = src;
    csr_ea[pos] = ea[e];
}

// ===== aggregation (one wave per dst node) + LayerNorm + GELU =====
__global__ __launch_bounds__(256) void k_agg_ln(const int* __restrict__ rowptr,
                                                const int* __restrict__ csr_src,
                                                const float* __restrict__ csr_ea,
                                                const float* __restrict__ ko,
                                                const float* __restrict__ qo,
                                                const float* __restrict__ vo,
                                                const float* __restrict__ aggin,
                                                const float* __restrict__ We,
                                                const float* __restrict__ be,
                                                const float* __restrict__ gamma,
                                                const float* __restrict__ beta,
                                                float* __restrict__ hout)
{
    int tid = threadIdx.x;
    int lane = tid & 63;
    int node = blockIdx.x * 4 + (tid >> 6);
    int j = lane * 2;
    float2 we  = *(const float2*)(We + j);
    float2 bev = *(const float2*)(be + j);
    float2 kd  = *(const float2*)(ko + (size_t)node * H + j);
    float2 acc = *(const float2*)(aggin + (size_t)node * H + j); // h@Ws + b_gcn
    int p = rowptr[node];
    int pend = rowptr[node + 1];

    for (; p + 2 <= pend; p += 2) {
        int s0 = csr_src[p];
        int s1 = csr_src[p + 1];
        float a0 = csr_ea[p];
        float a1 = csr_ea[p + 1];
        float2 q0 = *(const float2*)(qo + (size_t)s0 * H + j);
        float2 v0 = *(const float2*)(vo + (size_t)s0 * H + j);
        float2 q1 = *(const float2*)(qo + (size_t)s1 * H + j);
        float2 v1 = *(const float2*)(vo + (size_t)s1 * H + j);
        float e0x = fmaf(a0, we.x, bev.x), e0y = fmaf(a0, we.y, bev.y);
        float g0x = kd.x + q0.x + 2.f * e0x, g0y = kd.y + q0.y + 2.f * e0y;
        g0x = 1.f / (1.f + __expf(-g0x));
        g0y = 1.f / (1.f + __expf(-g0y));
        acc.x = fmaf(g0x, v0.x + e0x, acc.x);
        acc.y = fmaf(g0y, v0.y + e0y, acc.y);
        float e1x = fmaf(a1, we.x, bev.x), e1y = fmaf(a1, we.y, bev.y);
        float g1x = kd.x + q1.x + 2.f * e1x, g1y = kd.y + q1.y + 2.f * e1y;
        g1x = 1.f / (1.f + __expf(-g1x));
        g1y = 1.f / (1.f + __expf(-g1y));
        acc.x = fmaf(g1x, v1.x + e1x, acc.x);
        acc.y = fmaf(g1y, v1.y + e1y, acc.y);
    }
    if (p < pend) {
        int s0 = csr_src[p];
        float a0 = csr_ea[p];
        float2 q0 = *(const float2*)(qo + (size_t)s0 * H + j);
        float2 v0 = *(const float2*)(vo + (size_t)s0 * H + j);
        float e0x = fmaf(a0, we.x, bev.x), e0y = fmaf(a0, we.y, bev.y);
        float g0x = kd.x + q0.x + 2.f * e0x, g0y = kd.y + q0.y + 2.f * e0y;
        g0x = 1.f / (1.f + __expf(-g0x));
        g0y = 1.f / (1.f + __expf(-g0y));
        acc.x = fmaf(g0x, v0.x + e0x, acc.x);
        acc.y = fmaf(g0y, v0.y + e0y, acc.y);
    }

    // LayerNorm + exact GELU over the wave's 128 features
    float s  = acc.x + acc.y;
    float s2 = acc.x * acc.x + acc.y * acc.y;
    #pragma unroll
    for (int off = 32; off > 0; off >>= 1) {
        s  += __shfl_down(s, off);
        s2 += __shfl_down(s2, off);
    }
    s  = __shfl(s, 0);
    s2 = __shfl(s2, 0);
    float mu  = s * (1.f / H);
    float var = s2 * (1.f / H) - mu * mu;
    float rstd = rsqrtf(var + EPSF);
    float2 g = *(const float2*)(gamma + j);
    float2 b = *(const float2*)(beta + j);
    float y0 = (acc.x - mu) * rstd * g.x + b.x;
    float y1 = (acc.y - mu) * rstd * g.y + b.y;
    y0 = 0.5f * y0 * (1.f + erff(y0 * 0.70710678118f));
    y1 = 0.5f * y1 * (1.f + erff(y1 * 0.70710678118f));
    *(float2*)(hout + (size_t)node * H + j) = make_float2(y0, y1);
}

// ------------- out_proj: out = h @ W_out -------------
__global__ __launch_bounds__(256) void k_out(const float* __restrict__ h,
                                             const float* __restrict__ W, // 128x64
                                             float* __restrict__ out)
{
    __shared__ float hs[8 * H];
    int tid = threadIdx.x;
    int n0 = blockIdx.x * 8;
    ((float4*)hs)[tid] = ((const float4*)(h + (size_t)n0 * H))[tid];
    __syncthreads();
    int tx = tid & 63;
    int ty = tid >> 6; // 0..3, 2 nodes each
    float a0 = 0.f, a1 = 0.f;
    const float* hr = hs + ty * 2 * H;
    #pragma unroll 4
    for (int k = 0; k < H; ++k) {
        float w = W[k * DOUT + tx];
        a0 = fmaf(hr[k    ], w, a0);
        a1 = fmaf(hr[k + H], w, a1);
    }
    int nb = n0 + ty * 2;
    out[(size_t)(nb + 0) * DOUT + tx] = a0;
    out[(size_t)(nb + 1) * DOUT + tx] = a1;
}

extern "C" void kernel_launch(void* const* d_in, const int* in_sizes, int n_in,
                              void* d_out, int out_size, void* d_ws, size_t ws_size,
                              hipStream_t stream) {
    const float* x         = (const float*)d_in[0];
    const float* edge_attr = (const float*)d_in[1];
    const float* W_in      = (const float*)d_in[2];
    const float* b_in      = (const float*)d_in[3];
    const float* Wk        = (const float*)d_in[4];
    const float* bk        = (const float*)d_in[5];
    const float* Wq        = (const float*)d_in[6];
    const float* bq        = (const float*)d_in[7];
    const float* Wv        = (const float*)d_in[8];
    const float* bv        = (const float*)d_in[9];
    const float* We        = (const float*)d_in[10];
    const float* be        = (const float*)d_in[11];
    const float* Ws        = (const float*)d_in[12];
    const float* b_gcn     = (const float*)d_in[13];
    const float* gamma     = (const float*)d_in[14];
    const float* beta      = (const float*)d_in[15];
    const float* W_out     = (const float*)d_in[16];
    const int*   edge_index= (const int*)d_in[17];
    float* out = (float*)d_out;

    const size_t NH = (size_t)N_NODES * H;
    float* ws  = (float*)d_ws;
    float* h   = ws;
    float* ko  = h  + NH;
    float* qo  = ko + NH;
    float* vo  = qo + NH;
    float* agg = vo + NH;
    int*   deg     = (int*)(agg + NH);
    int*   fill    = deg + N_NODES;
    int*   rowptr  = fill + N_NODES;
    int*   csr_src = rowptr + (N_NODES + 1);
    float* csr_ea  = (float*)(csr_src + E_EDGES);

    // CSR build (edge_index constant across layers)
    k_zero<<<(N_NODES + 255) / 256, 256, 0, stream>>>(deg, fill);
    k_hist<<<E_EDGES / 256, 256, 0, stream>>>(edge_index, deg);
    k_scan<<<1, 1024, 0, stream>>>(deg, rowptr);
    k_scatter<<<E_EDGES / 256, 256, 0, stream>>>(edge_index, edge_attr, rowptr, fill,
                                                 csr_src, csr_ea);

    k_in_proj<<<N_NODES / 8, 256, 0, stream>>>(x, W_in, b_in, h);
    for (int l = 0; l < 3; ++l) {
        k_qkvs<<<N_NODES / 8, 256, 0, stream>>>(h,
            Wk + (size_t)l * H * H, bk + l * H,
            Wq + (size_t)l * H * H, bq + l * H,
            Wv + (size_t)l * H * H, bv + l * H,
            Ws + (size_t)l * H * H, b_gcn + l * H,
            ko, qo, vo, agg);
        k_agg_ln<<<N_NODES / 4, 256, 0, stream>>>(rowptr, csr_src, csr_ea,
                                                  ko, qo, vo, agg,
                                                  We + l * H, be + l * H,
                                                  gamma + l * H, beta + l * H, h);
    }
    k_out<<<N_NODES / 8, 256, 0, stream>>>(h, W_out, out);
}

// Round 3
// 673.238 us; speedup vs baseline: 3.7650x; 1.5280x over previous
//
#include <hip/hip_runtime.h>

#define N_NODES 50000
#define E_EDGES 800000
#define DIN 256
#define H 128
#define DOUT 64
#define EPSF 1e-5f

typedef __bf16 bf16x8 __attribute__((ext_vector_type(8)));
typedef float  f32x4  __attribute__((ext_vector_type(4)));
typedef unsigned short ushort_t;
typedef unsigned int   uint_t;

__device__ inline float bf2f(uint_t u) {
    union { uint_t i; float f; } v; v.i = u << 16; return v.f;
}
__device__ inline ushort_t f2bf(float f) {
    uint_t u = __float_as_uint(f);
    uint_t r = (u + 0x7fffu + ((u >> 16) & 1u)) >> 16;
    return (ushort_t)r;
}

// ---------------- conversions / packing ----------------
__global__ __launch_bounds__(256) void k_convx(const float* __restrict__ x, ushort_t* __restrict__ xb)
{
    int i = blockIdx.x * 256 + threadIdx.x; // 4 elems each, total N*DIN/4
    float4 v = ((const float4*)x)[i];
    ushort4 o;
    o.x = f2bf(v.x); o.y = f2bf(v.y); o.z = f2bf(v.z); o.w = f2bf(v.w);
    ((ushort4*)xb)[i] = o;
}

// pack all 3 layers of [Wk|Wq|Wv|Ws] into B^T layout: Bq[l][c][k], c in 0..511
__global__ __launch_bounds__(256) void k_pack_qkvs(const float* __restrict__ Wk, const float* __restrict__ Wq,
                                                   const float* __restrict__ Wv, const float* __restrict__ Ws,
                                                   ushort_t* __restrict__ Bq)
{
    int t = blockIdx.x * 256 + threadIdx.x;   // 3*512*128
    int l = t >> 16;
    int r = t & 65535;
    int c = r >> 7;
    int k = r & 127;
    int m = c >> 7;
    int cm = c & 127;
    const float* W = (m == 0) ? Wk : (m == 1) ? Wq : (m == 2) ? Wv : Ws;
    Bq[t] = f2bf(W[(size_t)l * H * H + k * H + cm]);
}

__global__ __launch_bounds__(256) void k_pack_in(const float* __restrict__ W_in, ushort_t* __restrict__ Bin)
{
    int t = blockIdx.x * 256 + threadIdx.x;   // 128*256
    int c = t >> 8;
    int k = t & 255;
    Bin[t] = f2bf(W_in[k * H + c]);
}

__global__ __launch_bounds__(256) void k_pack_out(const float* __restrict__ W_out, ushort_t* __restrict__ Bout)
{
    int t = blockIdx.x * 256 + threadIdx.x;   // 64*128
    int c = t >> 7;
    int k = t & 127;
    Bout[t] = f2bf(W_out[k * DOUT + c]);
}

// ---------------- in_proj MFMA: h = bf16(x @ W_in + b_in) ----------------
// wave computes 16 rows x 32 cols. K=256 (8 k-steps), NF=2, CG=4. blocks = 3125.
__global__ __launch_bounds__(256) void k_in_mfma(const ushort_t* __restrict__ xb,
                                                 const ushort_t* __restrict__ Bin,
                                                 const float* __restrict__ b_in,
                                                 ushort_t* __restrict__ hb)
{
    int gw = blockIdx.x * 4 + (threadIdx.x >> 6);
    int lane = threadIdx.x & 63;
    int rg = gw >> 2, cg = gw & 3;
    int r0 = rg * 16, c0 = cg * 32;
    const ushort_t* Ap = xb + (size_t)(r0 + (lane & 15)) * DIN + 8 * (lane >> 4);
    const ushort_t* Bp = Bin + (size_t)(c0 + (lane & 15)) * DIN + 8 * (lane >> 4);
    f32x4 acc[2];
    acc[0] = (f32x4){0.f, 0.f, 0.f, 0.f};
    acc[1] = (f32x4){0.f, 0.f, 0.f, 0.f};
    #pragma unroll
    for (int ks = 0; ks < 8; ++ks) {
        bf16x8 a = *(const bf16x8*)(Ap + ks * 32);
        bf16x8 b0 = *(const bf16x8*)(Bp + ks * 32);
        bf16x8 b1 = *(const bf16x8*)(Bp + 16 * DIN + ks * 32);
        acc[0] = __builtin_amdgcn_mfma_f32_16x16x32_bf16(a, b0, acc[0], 0, 0, 0);
        acc[1] = __builtin_amdgcn_mfma_f32_16x16x32_bf16(a, b1, acc[1], 0, 0, 0);
    }
    int rowb = r0 + ((lane >> 4) << 2);
    #pragma unroll
    for (int nf = 0; nf < 2; ++nf) {
        int col = c0 + nf * 16 + (lane & 15);
        float bb = b_in[col];
        #pragma unroll
        for (int j = 0; j < 4; ++j)
            hb[(size_t)(rowb + j) * H + col] = f2bf(acc[nf][j] + bb);
    }
}

// ---------------- qkvs MFMA: [k|q|v|agg] = h @ [Wk|Wq|Wv|Ws] + bias ----------------
// wave: 16 rows x 64 cols. K=128 (4 k-steps), NF=4, CG=8. blocks = 6250.
__global__ __launch_bounds__(256) void k_qkvs_mfma(const ushort_t* __restrict__ hb,
                                                   const ushort_t* __restrict__ Bq, // [512][128]
                                                   const float* __restrict__ bk, const float* __restrict__ bq,
                                                   const float* __restrict__ bv, const float* __restrict__ bs,
                                                   ushort_t* __restrict__ ko, ushort_t* __restrict__ qo,
                                                   ushort_t* __restrict__ vo, float* __restrict__ agg)
{
    int gw = blockIdx.x * 4 + (threadIdx.x >> 6);
    int lane = threadIdx.x & 63;
    int rg = gw >> 3, cg = gw & 7;
    int r0 = rg * 16, c0 = cg * 64;
    const ushort_t* Ap = hb + (size_t)(r0 + (lane & 15)) * H + 8 * (lane >> 4);
    const ushort_t* Bp = Bq + (size_t)(c0 + (lane & 15)) * H + 8 * (lane >> 4);
    f32x4 acc[4];
    #pragma unroll
    for (int nf = 0; nf < 4; ++nf) acc[nf] = (f32x4){0.f, 0.f, 0.f, 0.f};
    #pragma unroll
    for (int ks = 0; ks < 4; ++ks) {
        bf16x8 a = *(const bf16x8*)(Ap + ks * 32);
        #pragma unroll
        for (int nf = 0; nf < 4; ++nf) {
            bf16x8 b = *(const bf16x8*)(Bp + nf * 16 * H + ks * 32);
            acc[nf] = __builtin_amdgcn_mfma_f32_16x16x32_bf16(a, b, acc[nf], 0, 0, 0);
        }
    }
    int mat = cg >> 1;                     // 0=k,1=q,2=v,3=self
    int rowb = r0 + ((lane >> 4) << 2);
    const float* bias = (mat == 0) ? bk : (mat == 1) ? bq : (mat == 2) ? bv : bs;
    if (mat < 3) {
        ushort_t* D = (mat == 0) ? ko : (mat == 1) ? qo : vo;
        #pragma unroll
        for (int nf = 0; nf < 4; ++nf) {
            int col = ((cg & 1) << 6) + nf * 16 + (lane & 15);
            float bb = bias[col];
            #pragma unroll
            for (int j = 0; j < 4; ++j)
                D[(size_t)(rowb + j) * H + col] = f2bf(acc[nf][j] + bb);
        }
    } else {
        #pragma unroll
        for (int nf = 0; nf < 4; ++nf) {
            int col = ((cg & 1) << 6) + nf * 16 + (lane & 15);
            float bb = bias[col];
            #pragma unroll
            for (int j = 0; j < 4; ++j)
                agg[(size_t)(rowb + j) * H + col] = acc[nf][j] + bb;
        }
    }
}

// ================= CSR build (once per launch) =================
__global__ __launch_bounds__(256) void k_zero(int* __restrict__ deg, int* __restrict__ fill)
{
    int i = blockIdx.x * 256 + threadIdx.x;
    if (i < N_NODES) { deg[i] = 0; fill[i] = 0; }
}

__global__ __launch_bounds__(256) void k_hist(const int* __restrict__ ei, int* __restrict__ deg)
{
    int e = blockIdx.x * 256 + threadIdx.x;
    int dst = ei[E_EDGES + e];
    atomicAdd(&deg[dst], 1);
}

__global__ __launch_bounds__(1024) void k_scan(const int* __restrict__ deg, int* __restrict__ rowptr)
{
    __shared__ int wsum[16];
    int tid = threadIdx.x;
    const int CH = (N_NODES + 1023) / 1024;
    int beg = tid * CH;
    int end = beg + CH; if (end > N_NODES) end = N_NODES; if (beg > N_NODES) beg = N_NODES;
    int local = 0;
    for (int i = beg; i < end; ++i) local += deg[i];
    int lane = tid & 63, wid = tid >> 6;
    int v = local;
    #pragma unroll
    for (int off = 1; off < 64; off <<= 1) {
        int t = __shfl_up(v, off);
        if (lane >= off) v += t;
    }
    if (lane == 63) wsum[wid] = v;
    __syncthreads();
    if (wid == 0 && lane < 16) {
        int s = wsum[lane];
        #pragma unroll
        for (int off = 1; off < 16; off <<= 1) {
            int t = __shfl_up(s, off);
            if (lane >= off) s += t;
        }
        wsum[lane] = s;
    }
    __syncthreads();
    int waveoff = (wid > 0) ? wsum[wid - 1] : 0;
    int run = v - local + waveoff;
    for (int i = beg; i < end; ++i) { rowptr[i] = run; run += deg[i]; }
    if (tid == 1023) rowptr[N_NODES] = run;
}

__global__ __launch_bounds__(256) void k_scatter(const int* __restrict__ ei,
                                                 const float* __restrict__ ea,
                                                 const int* __restrict__ rowptr,
                                                 int* __restrict__ fill,
                                                 int* __restrict__ csr_src,
                                                 float* __restrict__ csr_ea)
{
    int e = blockIdx.x * 256 + threadIdx.x;
    int src = ei[e];
    int dst = ei[E_EDGES + e];
    int pos = rowptr[dst] + atomicAdd(&fill[dst], 1);
    csr_src[pos] = src;
    csr_ea[pos] = ea[e];
}

// ===== aggregation (one wave per dst node) + LayerNorm + GELU -> h (bf16) =====
__global__ __launch_bounds__(256) void k_agg_ln(const int* __restrict__ rowptr,
                                                const int* __restrict__ csr_src,
                                                const float* __restrict__ csr_ea,
                                                const ushort_t* __restrict__ ko,
                                                const ushort_t* __restrict__ qo,
                                                const ushort_t* __restrict__ vo,
                                                const float* __restrict__ aggin,
                                                const float* __restrict__ We,
                                                const float* __restrict__ be,
                                                const float* __restrict__ gamma,
                                                const float* __restrict__ beta,
                                                ushort_t* __restrict__ hout)
{
    int tid = threadIdx.x;
    int lane = tid & 63;
    int node = blockIdx.x * 4 + (tid >> 6);
    int j = lane * 2;
    const uint_t* kou = (const uint_t*)ko;
    const uint_t* qou = (const uint_t*)qo;
    const uint_t* vou = (const uint_t*)vo;

    float2 we  = *(const float2*)(We + j);
    float2 bev = *(const float2*)(be + j);
    uint_t kdu = kou[(size_t)node * 64 + lane];
    float kdx = bf2f(kdu & 0xffffu), kdy = bf2f(kdu >> 16);
    float2 acc = ((const float2*)aggin)[(size_t)node * 64 + lane]; // h@Ws + b_gcn
    int p = rowptr[node];
    int pend = rowptr[node + 1];

    for (; p + 2 <= pend; p += 2) {
        int s0 = csr_src[p];
        int s1 = csr_src[p + 1];
        float a0 = csr_ea[p];
        float a1 = csr_ea[p + 1];
        uint_t q0u = qou[(size_t)s0 * 64 + lane];
        uint_t v0u = vou[(size_t)s0 * 64 + lane];
        uint_t q1u = qou[(size_t)s1 * 64 + lane];
        uint_t v1u = vou[(size_t)s1 * 64 + lane];
        float e0x = fmaf(a0, we.x, bev.x), e0y = fmaf(a0, we.y, bev.y);
        float g0x = kdx + bf2f(q0u & 0xffffu) + 2.f * e0x;
        float g0y = kdy + bf2f(q0u >> 16)     + 2.f * e0y;
        g0x = 1.f / (1.f + __expf(-g0x));
        g0y = 1.f / (1.f + __expf(-g0y));
        acc.x = fmaf(g0x, bf2f(v0u & 0xffffu) + e0x, acc.x);
        acc.y = fmaf(g0y, bf2f(v0u >> 16)     + e0y, acc.y);
        float e1x = fmaf(a1, we.x, bev.x), e1y = fmaf(a1, we.y, bev.y);
        float g1x = kdx + bf2f(q1u & 0xffffu) + 2.f * e1x;
        float g1y = kdy + bf2f(q1u >> 16)     + 2.f * e1y;
        g1x = 1.f / (1.f + __expf(-g1x));
        g1y = 1.f / (1.f + __expf(-g1y));
        acc.x = fmaf(g1x, bf2f(v1u & 0xffffu) + e1x, acc.x);
        acc.y = fmaf(g1y, bf2f(v1u >> 16)     + e1y, acc.y);
    }
    if (p < pend) {
        int s0 = csr_src[p];
        float a0 = csr_ea[p];
        uint_t q0u = qou[(size_t)s0 * 64 + lane];
        uint_t v0u = vou[(size_t)s0 * 64 + lane];
        float e0x = fmaf(a0, we.x, bev.x), e0y = fmaf(a0, we.y, bev.y);
        float g0x = kdx + bf2f(q0u & 0xffffu) + 2.f * e0x;
        float g0y = kdy + bf2f(q0u >> 16)     + 2.f * e0y;
        g0x = 1.f / (1.f + __expf(-g0x));
        g0y = 1.f / (1.f + __expf(-g0y));
        acc.x = fmaf(g0x, bf2f(v0u & 0xffffu) + e0x, acc.x);
        acc.y = fmaf(g0y, bf2f(v0u >> 16)     + e0y, acc.y);
    }

    float s  = acc.x + acc.y;
    float s2 = acc.x * acc.x + acc.y * acc.y;
    #pragma unroll
    for (int off = 32; off > 0; off >>= 1) {
        s  += __shfl_down(s, off);
        s2 += __shfl_down(s2, off);
    }
    s  = __shfl(s, 0);
    s2 = __shfl(s2, 0);
    float mu  = s * (1.f / H);
    float var = s2 * (1.f / H) - mu * mu;
    float rstd = rsqrtf(var + EPSF);
    float2 g = *(const float2*)(gamma + j);
    float2 b = *(const float2*)(beta + j);
    float y0 = (acc.x - mu) * rstd * g.x + b.x;
    float y1 = (acc.y - mu) * rstd * g.y + b.y;
    y0 = 0.5f * y0 * (1.f + erff(y0 * 0.70710678118f));
    y1 = 0.5f * y1 * (1.f + erff(y1 * 0.70710678118f));
    uint_t packed = ((uint_t)f2bf(y1) << 16) | (uint_t)f2bf(y0);
    ((uint_t*)hout)[(size_t)node * 64 + lane] = packed;
}

// ---------------- out_proj MFMA: out = h @ W_out (fp32 out) ----------------
// wave: 16 rows x 32 cols. K=128, NF=2, CG=2. waves=6250, blocks=1563 (guard).
__global__ __launch_bounds__(256) void k_out_mfma(const ushort_t* __restrict__ hb,
                                                  const ushort_t* __restrict__ Bout, // [64][128]
                                                  float* __restrict__ out)
{
    int gw = blockIdx.x * 4 + (threadIdx.x >> 6);
    if (gw >= 6250) return;
    int lane = threadIdx.x & 63;
    int rg = gw >> 1, cg = gw & 1;
    int r0 = rg * 16, c0 = cg * 32;
    const ushort_t* Ap = hb + (size_t)(r0 + (lane & 15)) * H + 8 * (lane >> 4);
    const ushort_t* Bp = Bout + (size_t)(c0 + (lane & 15)) * H + 8 * (lane >> 4);
    f32x4 acc[2];
    acc[0] = (f32x4){0.f, 0.f, 0.f, 0.f};
    acc[1] = (f32x4){0.f, 0.f, 0.f, 0.f};
    #pragma unroll
    for (int ks = 0; ks < 4; ++ks) {
        bf16x8 a = *(const bf16x8*)(Ap + ks * 32);
        bf16x8 b0 = *(const bf16x8*)(Bp + ks * 32);
        bf16x8 b1 = *(const bf16x8*)(Bp + 16 * H + ks * 32);
        acc[0] = __builtin_amdgcn_mfma_f32_16x16x32_bf16(a, b0, acc[0], 0, 0, 0);
        acc[1] = __builtin_amdgcn_mfma_f32_16x16x32_bf16(a, b1, acc[1], 0, 0, 0);
    }
    int rowb = r0 + ((lane >> 4) << 2);
    #pragma unroll
    for (int nf = 0; nf < 2; ++nf) {
        int col = c0 + nf * 16 + (lane & 15);
        #pragma unroll
        for (int j = 0; j < 4; ++j)
            out[(size_t)(rowb + j) * DOUT + col] = acc[nf][j];
    }
}

extern "C" void kernel_launch(void* const* d_in, const int* in_sizes, int n_in,
                              void* d_out, int out_size, void* d_ws, size_t ws_size,
                              hipStream_t stream) {
    const float* x         = (const float*)d_in[0];
    const float* edge_attr = (const float*)d_in[1];
    const float* W_in      = (const float*)d_in[2];
    const float* b_in      = (const float*)d_in[3];
    const float* Wk        = (const float*)d_in[4];
    const float* bk        = (const float*)d_in[5];
    const float* Wq        = (const float*)d_in[6];
    const float* bq        = (const float*)d_in[7];
    const float* Wv        = (const float*)d_in[8];
    const float* bv        = (const float*)d_in[9];
    const float* We        = (const float*)d_in[10];
    const float* be        = (const float*)d_in[11];
    const float* Ws        = (const float*)d_in[12];
    const float* b_gcn     = (const float*)d_in[13];
    const float* gamma     = (const float*)d_in[14];
    const float* beta      = (const float*)d_in[15];
    const float* W_out     = (const float*)d_in[16];
    const int*   edge_index= (const int*)d_in[17];
    float* out = (float*)d_out;

    char* wsb = (char*)d_ws;
    const size_t NH2 = (size_t)N_NODES * H * 2;     // bf16 node matrix bytes
    ushort_t* hb  = (ushort_t*)wsb;                  wsb += NH2;
    ushort_t* ko  = (ushort_t*)wsb;                  wsb += NH2;
    ushort_t* qo  = (ushort_t*)wsb;                  wsb += NH2;
    ushort_t* vo  = (ushort_t*)wsb;                  wsb += NH2;
    float*    agg = (float*)wsb;                     wsb += (size_t)N_NODES * H * 4;
    ushort_t* xb  = (ushort_t*)wsb;                  wsb += (size_t)N_NODES * DIN * 2;
    ushort_t* Bq  = (ushort_t*)wsb;                  wsb += 3 * 512 * 128 * 2;
    ushort_t* Bin = (ushort_t*)wsb;                  wsb += 128 * 256 * 2;
    ushort_t* Bout= (ushort_t*)wsb;                  wsb += 64 * 128 * 2;
    int*   csr_src = (int*)wsb;                      wsb += (size_t)E_EDGES * 4;
    float* csr_ea  = (float*)wsb;                    wsb += (size_t)E_EDGES * 4;
    int*   deg     = (int*)wsb;                      wsb += N_NODES * 4;
    int*   fill    = (int*)wsb;                      wsb += N_NODES * 4;
    int*   rowptr  = (int*)wsb;                      wsb += (N_NODES + 1) * 4;

    // CSR build (edge_index constant across layers)
    k_zero<<<(N_NODES + 255) / 256, 256, 0, stream>>>(deg, fill);
    k_hist<<<E_EDGES / 256, 256, 0, stream>>>(edge_index, deg);
    k_scan<<<1, 1024, 0, stream>>>(deg, rowptr);
    k_scatter<<<E_EDGES / 256, 256, 0, stream>>>(edge_index, edge_attr, rowptr, fill,
                                                 csr_src, csr_ea);

    // conversions + weight packing
    k_convx<<<(N_NODES * DIN / 4 + 255) / 256, 256, 0, stream>>>(x, xb);
    k_pack_qkvs<<<3 * 512 * 128 / 256, 256, 0, stream>>>(Wk, Wq, Wv, Ws, Bq);
    k_pack_in<<<128 * 256 / 256, 256, 0, stream>>>(W_in, Bin);
    k_pack_out<<<64 * 128 / 256, 256, 0, stream>>>(W_out, Bout);

    k_in_mfma<<<3125, 256, 0, stream>>>(xb, Bin, b_in, hb);
    for (int l = 0; l < 3; ++l) {
        k_qkvs_mfma<<<6250, 256, 0, stream>>>(hb, Bq + (size_t)l * 512 * 128,
                                              bk + l * H, bq + l * H, bv + l * H, b_gcn + l * H,
                                              ko, qo, vo, agg);
        k_agg_ln<<<N_NODES / 4, 256, 0, stream>>>(rowptr, csr_src, csr_ea,
                                                  ko, qo, vo, agg,
                                                  We + l * H, be + l * H,
                                                  gamma + l * H, beta + l * H, hb);
    }
    k_out_mfma<<<1563, 256, 0, stream>>>(hb, Bout, out);
}

// Round 4
// 606.942 us; speedup vs baseline: 4.1763x; 1.1092x over previous
//
#include <hip/hip_runtime.h>

#define N_NODES 50000
#define E_EDGES 800000
#define DIN 256
#define H 128
#define DOUT 64
#define EPSF 1e-5f

typedef __bf16 bf16x8 __attribute__((ext_vector_type(8)));
typedef float  f32x4  __attribute__((ext_vector_type(4)));
typedef unsigned short ushort_t;
typedef unsigned int   uint_t;

__device__ inline float bf2f(uint_t u) {
    union { uint_t i; float f; } v; v.i = u << 16; return v.f;
}
__device__ inline ushort_t f2bf(float f) {
    uint_t u = __float_as_uint(f);
    uint_t r = (u + 0x7fffu + ((u >> 16) & 1u)) >> 16;
    return (ushort_t)r;
}

// ---------------- x -> bf16 ----------------
__global__ __launch_bounds__(256) void k_convx(const float* __restrict__ x, ushort_t* __restrict__ xb)
{
    int i = blockIdx.x * 256 + threadIdx.x;
    float4 v = ((const float4*)x)[i];
    ushort4 o;
    o.x = f2bf(v.x); o.y = f2bf(v.y); o.z = f2bf(v.z); o.w = f2bf(v.w);
    ((ushort4*)xb)[i] = o;
}

// ----------- merged weight packing (B^T layouts) -----------
// region 0: Bq[l][c][k]   3*512*128 = 196608   (c: 0..127 k,128..255 q,256..383 v,384..511 s)
// region 1: Bin[c][k]     128*256   =  32768
// region 2: Bout[c][k]    64*128    =   8192
__global__ __launch_bounds__(256) void k_pack(const float* __restrict__ Wk, const float* __restrict__ Wq,
                                              const float* __restrict__ Wv, const float* __restrict__ Ws,
                                              const float* __restrict__ W_in, const float* __restrict__ W_out,
                                              ushort_t* __restrict__ Bq, ushort_t* __restrict__ Bin,
                                              ushort_t* __restrict__ Bout)
{
    int t = blockIdx.x * 256 + threadIdx.x;
    if (t < 196608) {
        int l = t >> 16;
        int r = t & 65535;
        int c = r >> 7;
        int k = r & 127;
        int m = c >> 7;
        int cm = c & 127;
        const float* W = (m == 0) ? Wk : (m == 1) ? Wq : (m == 2) ? Wv : Ws;
        Bq[t] = f2bf(W[(size_t)l * H * H + k * H + cm]);
    } else if (t < 229376) {
        int t2 = t - 196608;
        int c = t2 >> 8;
        int k = t2 & 255;
        Bin[t2] = f2bf(W_in[k * H + c]);
    } else {
        int t3 = t - 229376;
        int c = t3 >> 7;
        int k = t3 & 127;
        Bout[t3] = f2bf(W_out[k * DOUT + c]);
    }
}

// ---------------- in_proj MFMA: h = bf16(x @ W_in + b_in) ----------------
__global__ __launch_bounds__(256) void k_in_mfma(const ushort_t* __restrict__ xb,
                                                 const ushort_t* __restrict__ Bin,
                                                 const float* __restrict__ b_in,
                                                 ushort_t* __restrict__ hb)
{
    int gw = blockIdx.x * 4 + (threadIdx.x >> 6);
    int lane = threadIdx.x & 63;
    int rg = gw >> 2, cg = gw & 3;
    int r0 = rg * 16, c0 = cg * 32;
    const ushort_t* Ap = xb + (size_t)(r0 + (lane & 15)) * DIN + 8 * (lane >> 4);
    const ushort_t* Bp = Bin + (size_t)(c0 + (lane & 15)) * DIN + 8 * (lane >> 4);
    f32x4 acc[2];
    acc[0] = (f32x4){0.f, 0.f, 0.f, 0.f};
    acc[1] = (f32x4){0.f, 0.f, 0.f, 0.f};
    #pragma unroll
    for (int ks = 0; ks < 8; ++ks) {
        bf16x8 a = *(const bf16x8*)(Ap + ks * 32);
        bf16x8 b0 = *(const bf16x8*)(Bp + ks * 32);
        bf16x8 b1 = *(const bf16x8*)(Bp + 16 * DIN + ks * 32);
        acc[0] = __builtin_amdgcn_mfma_f32_16x16x32_bf16(a, b0, acc[0], 0, 0, 0);
        acc[1] = __builtin_amdgcn_mfma_f32_16x16x32_bf16(a, b1, acc[1], 0, 0, 0);
    }
    int rowb = r0 + ((lane >> 4) << 2);
    #pragma unroll
    for (int nf = 0; nf < 2; ++nf) {
        int col = c0 + nf * 16 + (lane & 15);
        float bb = b_in[col];
        #pragma unroll
        for (int j = 0; j < 4; ++j)
            hb[(size_t)(rowb + j) * H + col] = f2bf(acc[nf][j] + bb);
    }
}

// ------ qkvs MFMA: k -> ko (bf16), q/v -> interleaved qv, self -> agg (f32) ------
// qv layout: per node 64 entries of uint2{ qpack(2bf16), vpack(2bf16) }, entry f = feats (2f,2f+1)
__global__ __launch_bounds__(256) void k_qkvs_mfma(const ushort_t* __restrict__ hb,
                                                   const ushort_t* __restrict__ Bq, // [512][128]
                                                   const float* __restrict__ bk, const float* __restrict__ bq,
                                                   const float* __restrict__ bv, const float* __restrict__ bs,
                                                   ushort_t* __restrict__ ko, ushort_t* __restrict__ qv,
                                                   float* __restrict__ agg)
{
    int gw = blockIdx.x * 4 + (threadIdx.x >> 6);
    int lane = threadIdx.x & 63;
    int rg = gw >> 3, cg = gw & 7;
    int r0 = rg * 16, c0 = cg * 64;
    const ushort_t* Ap = hb + (size_t)(r0 + (lane & 15)) * H + 8 * (lane >> 4);
    const ushort_t* Bp = Bq + (size_t)(c0 + (lane & 15)) * H + 8 * (lane >> 4);
    f32x4 acc[4];
    #pragma unroll
    for (int nf = 0; nf < 4; ++nf) acc[nf] = (f32x4){0.f, 0.f, 0.f, 0.f};
    #pragma unroll
    for (int ks = 0; ks < 4; ++ks) {
        bf16x8 a = *(const bf16x8*)(Ap + ks * 32);
        #pragma unroll
        for (int nf = 0; nf < 4; ++nf) {
            bf16x8 b = *(const bf16x8*)(Bp + nf * 16 * H + ks * 32);
            acc[nf] = __builtin_amdgcn_mfma_f32_16x16x32_bf16(a, b, acc[nf], 0, 0, 0);
        }
    }
    int mat = cg >> 1;                     // 0=k,1=q,2=v,3=self
    int rowb = r0 + ((lane >> 4) << 2);
    const float* bias = (mat == 0) ? bk : (mat == 1) ? bq : (mat == 2) ? bv : bs;
    if (mat == 0) {
        #pragma unroll
        for (int nf = 0; nf < 4; ++nf) {
            int col = ((cg & 1) << 6) + nf * 16 + (lane & 15);
            float bb = bias[col];
            #pragma unroll
            for (int j = 0; j < 4; ++j)
                ko[(size_t)(rowb + j) * H + col] = f2bf(acc[nf][j] + bb);
        }
    } else if (mat < 3) {
        int voff = (mat == 2) ? 2 : 0;     // q at ushorts 0..1, v at 2..3
        #pragma unroll
        for (int nf = 0; nf < 4; ++nf) {
            int col = ((cg & 1) << 6) + nf * 16 + (lane & 15);
            float bb = bias[col];
            int ent = ((col >> 1) << 2) + (col & 1) + voff;
            #pragma unroll
            for (int j = 0; j < 4; ++j)
                qv[(size_t)(rowb + j) * 256 + ent] = f2bf(acc[nf][j] + bb);
        }
    } else {
        #pragma unroll
        for (int nf = 0; nf < 4; ++nf) {
            int col = ((cg & 1) << 6) + nf * 16 + (lane & 15);
            float bb = bias[col];
            #pragma unroll
            for (int j = 0; j < 4; ++j)
                agg[(size_t)(rowb + j) * H + col] = acc[nf][j] + bb;
        }
    }
}

// ================= CSR build =================
__global__ __launch_bounds__(256) void k_hist(const int* __restrict__ ei, int* __restrict__ deg)
{
    int e = blockIdx.x * 256 + threadIdx.x;
    int dst = ei[E_EDGES + e];
    atomicAdd(&deg[dst], 1);
}

__global__ __launch_bounds__(1024) void k_scan(const int* __restrict__ deg, int* __restrict__ rowptr)
{
    __shared__ int wsum[16];
    int tid = threadIdx.x;
    const int CH = (N_NODES + 1023) / 1024;
    int beg = tid * CH;
    int end = beg + CH; if (end > N_NODES) end = N_NODES; if (beg > N_NODES) beg = N_NODES;
    int local = 0;
    for (int i = beg; i < end; ++i) local += deg[i];
    int lane = tid & 63, wid = tid >> 6;
    int v = local;
    #pragma unroll
    for (int off = 1; off < 64; off <<= 1) {
        int t = __shfl_up(v, off);
        if (lane >= off) v += t;
    }
    if (lane == 63) wsum[wid] = v;
    __syncthreads();
    if (wid == 0 && lane < 16) {
        int s = wsum[lane];
        #pragma unroll
        for (int off = 1; off < 16; off <<= 1) {
            int t = __shfl_up(s, off);
            if (lane >= off) s += t;
        }
        wsum[lane] = s;
    }
    __syncthreads();
    int waveoff = (wid > 0) ? wsum[wid - 1] : 0;
    int run = v - local + waveoff;
    for (int i = beg; i < end; ++i) { rowptr[i] = run; run += deg[i]; }
    if (tid == 1023) rowptr[N_NODES] = run;
}

__global__ __launch_bounds__(256) void k_scatter(const int* __restrict__ ei,
                                                 const float* __restrict__ ea,
                                                 const int* __restrict__ rowptr,
                                                 int* __restrict__ fill,
                                                 uint2* __restrict__ csr)
{
    int e = blockIdx.x * 256 + threadIdx.x;
    int src = ei[e];
    int dst = ei[E_EDGES + e];
    int pos = rowptr[dst] + atomicAdd(&fill[dst], 1);
    csr[pos] = make_uint2((uint_t)src, __float_as_uint(ea[e]));
}

// ===== aggregation (one wave per dst node) + LayerNorm + GELU -> h (bf16) =====
__global__ __launch_bounds__(256) void k_agg_ln(const int* __restrict__ rowptr,
                                                const uint2* __restrict__ csr,
                                                const ushort_t* __restrict__ ko,
                                                const uint2* __restrict__ qvp,
                                                const float* __restrict__ aggin,
                                                const float* __restrict__ We,
                                                const float* __restrict__ be,
                                                const float* __restrict__ gamma,
                                                const float* __restrict__ beta,
                                                ushort_t* __restrict__ hout)
{
    int tid = threadIdx.x;
    int lane = tid & 63;
    int node = blockIdx.x * 4 + (tid >> 6);
    int j = lane * 2;

    float2 we  = *(const float2*)(We + j);
    float2 bev = *(const float2*)(be + j);
    uint_t kdu = ((const uint_t*)ko)[(size_t)node * 64 + lane];
    float kdx = bf2f(kdu & 0xffffu), kdy = bf2f(kdu >> 16);
    float2 acc = ((const float2*)aggin)[(size_t)node * 64 + lane]; // h@Ws + b_gcn
    int p = rowptr[node];
    int pend = rowptr[node + 1];

#define EDGE(c, u) {                                                          \
    float a  = __uint_as_float((c).y);                                        \
    float qx = bf2f((u).x & 0xffffu), qy = bf2f((u).x >> 16);                 \
    float vx = bf2f((u).y & 0xffffu), vy = bf2f((u).y >> 16);                 \
    float ex = fmaf(a, we.x, bev.x), ey = fmaf(a, we.y, bev.y);               \
    float gx = kdx + qx + 2.f * ex,  gy = kdy + qy + 2.f * ey;                \
    float sx = __builtin_amdgcn_rcpf(1.f + __expf(-gx));                      \
    float sy = __builtin_amdgcn_rcpf(1.f + __expf(-gy));                      \
    acc.x = fmaf(sx, vx + ex, acc.x);                                         \
    acc.y = fmaf(sy, vy + ey, acc.y); }

    for (; p + 4 <= pend; p += 4) {
        uint2 c0 = csr[p], c1 = csr[p + 1], c2 = csr[p + 2], c3 = csr[p + 3];
        uint2 u0 = qvp[c0.x * 64u + lane];
        uint2 u1 = qvp[c1.x * 64u + lane];
        uint2 u2 = qvp[c2.x * 64u + lane];
        uint2 u3 = qvp[c3.x * 64u + lane];
        EDGE(c0, u0); EDGE(c1, u1); EDGE(c2, u2); EDGE(c3, u3);
    }
    for (; p < pend; ++p) {
        uint2 c = csr[p];
        uint2 u = qvp[c.x * 64u + lane];
        EDGE(c, u);
    }
#undef EDGE

    float s  = acc.x + acc.y;
    float s2 = acc.x * acc.x + acc.y * acc.y;
    #pragma unroll
    for (int off = 32; off > 0; off >>= 1) {
        s  += __shfl_down(s, off);
        s2 += __shfl_down(s2, off);
    }
    s  = __shfl(s, 0);
    s2 = __shfl(s2, 0);
    float mu  = s * (1.f / H);
    float var = s2 * (1.f / H) - mu * mu;
    float rstd = rsqrtf(var + EPSF);
    float2 g = *(const float2*)(gamma + j);
    float2 b = *(const float2*)(beta + j);
    float y0 = (acc.x - mu) * rstd * g.x + b.x;
    float y1 = (acc.y - mu) * rstd * g.y + b.y;
    y0 = 0.5f * y0 * (1.f + erff(y0 * 0.70710678118f));
    y1 = 0.5f * y1 * (1.f + erff(y1 * 0.70710678118f));
    uint_t packed = ((uint_t)f2bf(y1) << 16) | (uint_t)f2bf(y0);
    ((uint_t*)hout)[(size_t)node * 64 + lane] = packed;
}

// ---------------- out_proj MFMA: out = h @ W_out (fp32 out) ----------------
__global__ __launch_bounds__(256) void k_out_mfma(const ushort_t* __restrict__ hb,
                                                  const ushort_t* __restrict__ Bout, // [64][128]
                                                  float* __restrict__ out)
{
    int gw = blockIdx.x * 4 + (threadIdx.x >> 6);
    if (gw >= 6250) return;
    int lane = threadIdx.x & 63;
    int rg = gw >> 1, cg = gw & 1;
    int r0 = rg * 16, c0 = cg * 32;
    const ushort_t* Ap = hb + (size_t)(r0 + (lane & 15)) * H + 8 * (lane >> 4);
    const ushort_t* Bp = Bout + (size_t)(c0 + (lane & 15)) * H + 8 * (lane >> 4);
    f32x4 acc[2];
    acc[0] = (f32x4){0.f, 0.f, 0.f, 0.f};
    acc[1] = (f32x4){0.f, 0.f, 0.f, 0.f};
    #pragma unroll
    for (int ks = 0; ks < 4; ++ks) {
        bf16x8 a = *(const bf16x8*)(Ap + ks * 32);
        bf16x8 b0 = *(const bf16x8*)(Bp + ks * 32);
        bf16x8 b1 = *(const bf16x8*)(Bp + 16 * H + ks * 32);
        acc[0] = __builtin_amdgcn_mfma_f32_16x16x32_bf16(a, b0, acc[0], 0, 0, 0);
        acc[1] = __builtin_amdgcn_mfma_f32_16x16x32_bf16(a, b1, acc[1], 0, 0, 0);
    }
    int rowb = r0 + ((lane >> 4) << 2);
    #pragma unroll
    for (int nf = 0; nf < 2; ++nf) {
        int col = c0 + nf * 16 + (lane & 15);
        #pragma unroll
        for (int j = 0; j < 4; ++j)
            out[(size_t)(rowb + j) * DOUT + col] = acc[nf][j];
    }
}

extern "C" void kernel_launch(void* const* d_in, const int* in_sizes, int n_in,
                              void* d_out, int out_size, void* d_ws, size_t ws_size,
                              hipStream_t stream) {
    const float* x         = (const float*)d_in[0];
    const float* edge_attr = (const float*)d_in[1];
    const float* W_in      = (const float*)d_in[2];
    const float* b_in      = (const float*)d_in[3];
    const float* Wk        = (const float*)d_in[4];
    const float* bk        = (const float*)d_in[5];
    const float* Wq        = (const float*)d_in[6];
    const float* bq        = (const float*)d_in[7];
    const float* Wv        = (const float*)d_in[8];
    const float* bv        = (const float*)d_in[9];
    const float* We        = (const float*)d_in[10];
    const float* be        = (const float*)d_in[11];
    const float* Ws        = (const float*)d_in[12];
    const float* b_gcn     = (const float*)d_in[13];
    const float* gamma     = (const float*)d_in[14];
    const float* beta      = (const float*)d_in[15];
    const float* W_out     = (const float*)d_in[16];
    const int*   edge_index= (const int*)d_in[17];
    float* out = (float*)d_out;

    char* wsb = (char*)d_ws;
    const size_t NH2 = (size_t)N_NODES * H * 2;
    ushort_t* hb  = (ushort_t*)wsb;                  wsb += NH2;
    ushort_t* ko  = (ushort_t*)wsb;                  wsb += NH2;
    ushort_t* qv  = (ushort_t*)wsb;                  wsb += (size_t)N_NODES * 512;
    float*    agg = (float*)wsb;                     wsb += (size_t)N_NODES * H * 4;
    ushort_t* xb  = (ushort_t*)wsb;                  wsb += (size_t)N_NODES * DIN * 2;
    ushort_t* Bq  = (ushort_t*)wsb;                  wsb += 3 * 512 * 128 * 2;
    ushort_t* Bin = (ushort_t*)wsb;                  wsb += 128 * 256 * 2;
    ushort_t* Bout= (ushort_t*)wsb;                  wsb += 64 * 128 * 2;
    uint2* csr    = (uint2*)wsb;                     wsb += (size_t)E_EDGES * 8;
    int*   deg    = (int*)wsb;                       wsb += N_NODES * 4;
    int*   fill   = (int*)wsb;                       wsb += N_NODES * 4;
    int*   rowptr = (int*)wsb;                       wsb += (N_NODES + 1) * 4;

    // CSR build (edge_index constant across layers)
    hipMemsetAsync(deg, 0, 2 * N_NODES * sizeof(int), stream); // zeroes deg + fill
    k_hist<<<E_EDGES / 256, 256, 0, stream>>>(edge_index, deg);
    k_scan<<<1, 1024, 0, stream>>>(deg, rowptr);
    k_scatter<<<E_EDGES / 256, 256, 0, stream>>>(edge_index, edge_attr, rowptr, fill, csr);

    // conversions + weight packing
    k_convx<<<(N_NODES * DIN / 4 + 255) / 256, 256, 0, stream>>>(x, xb);
    k_pack<<<928, 256, 0, stream>>>(Wk, Wq, Wv, Ws, W_in, W_out, Bq, Bin, Bout);

    k_in_mfma<<<3125, 256, 0, stream>>>(xb, Bin, b_in, hb);
    for (int l = 0; l < 3; ++l) {
        k_qkvs_mfma<<<6250, 256, 0, stream>>>(hb, Bq + (size_t)l * 512 * 128,
                                              bk + l * H, bq + l * H, bv + l * H, b_gcn + l * H,
                                              ko, qv, agg);
        k_agg_ln<<<N_NODES / 4, 256, 0, stream>>>(rowptr, csr, ko, (const uint2*)qv, agg,
                                                  We + l * H, be + l * H,
                                                  gamma + l * H, beta + l * H, hb);
    }
    k_out_mfma<<<1563, 256, 0, stream>>>(hb, Bout, out);
}

// Round 5
// 534.545 us; speedup vs baseline: 4.7419x; 1.1354x over previous
//
#include <hip/hip_runtime.h>

#define N_NODES 50000
#define E_EDGES 800000
#define DIN 256
#define H 128
#define DOUT 64
#define EPSF 1e-5f
#define NBLK 196   // ceil(N_NODES/256)

typedef __bf16 bf16x8 __attribute__((ext_vector_type(8)));
typedef float  f32x4  __attribute__((ext_vector_type(4)));
typedef unsigned short ushort_t;
typedef unsigned int   uint_t;

__device__ inline float bf2f(uint_t u) {
    union { uint_t i; float f; } v; v.i = u << 16; return v.f;
}
__device__ inline ushort_t f2bf(float f) {
    uint_t u = __float_as_uint(f);
    uint_t r = (u + 0x7fffu + ((u >> 16) & 1u)) >> 16;
    return (ushort_t)r;
}

// ---------------- x -> bf16 ----------------
__global__ __launch_bounds__(256) void k_convx(const float* __restrict__ x, ushort_t* __restrict__ xb)
{
    int i = blockIdx.x * 256 + threadIdx.x;
    float4 v = ((const float4*)x)[i];
    ushort4 o;
    o.x = f2bf(v.x); o.y = f2bf(v.y); o.z = f2bf(v.z); o.w = f2bf(v.w);
    ((ushort4*)xb)[i] = o;
}

// ----------- merged weight packing (B^T layouts) -----------
__global__ __launch_bounds__(256) void k_pack(const float* __restrict__ Wk, const float* __restrict__ Wq,
                                              const float* __restrict__ Wv, const float* __restrict__ Ws,
                                              const float* __restrict__ W_in, const float* __restrict__ W_out,
                                              ushort_t* __restrict__ Bq, ushort_t* __restrict__ Bin,
                                              ushort_t* __restrict__ Bout)
{
    int t = blockIdx.x * 256 + threadIdx.x;
    if (t < 196608) {
        int l = t >> 16;
        int r = t & 65535;
        int c = r >> 7;
        int k = r & 127;
        int m = c >> 7;
        int cm = c & 127;
        const float* W = (m == 0) ? Wk : (m == 1) ? Wq : (m == 2) ? Wv : Ws;
        Bq[t] = f2bf(W[(size_t)l * H * H + k * H + cm]);
    } else if (t < 229376) {
        int t2 = t - 196608;
        int c = t2 >> 8;
        int k = t2 & 255;
        Bin[t2] = f2bf(W_in[k * H + c]);
    } else {
        int t3 = t - 229376;
        int c = t3 >> 7;
        int k = t3 & 127;
        Bout[t3] = f2bf(W_out[k * DOUT + c]);
    }
}

// ---------------- in_proj MFMA: h = bf16(x @ W_in + b_in) ----------------
__global__ __launch_bounds__(256) void k_in_mfma(const ushort_t* __restrict__ xb,
                                                 const ushort_t* __restrict__ Bin,
                                                 const float* __restrict__ b_in,
                                                 ushort_t* __restrict__ hb)
{
    int gw = blockIdx.x * 4 + (threadIdx.x >> 6);
    int lane = threadIdx.x & 63;
    int rg = gw >> 2, cg = gw & 3;
    int r0 = rg * 16, c0 = cg * 32;
    const ushort_t* Ap = xb + (size_t)(r0 + (lane & 15)) * DIN + 8 * (lane >> 4);
    const ushort_t* Bp = Bin + (size_t)(c0 + (lane & 15)) * DIN + 8 * (lane >> 4);
    f32x4 acc[2];
    acc[0] = (f32x4){0.f, 0.f, 0.f, 0.f};
    acc[1] = (f32x4){0.f, 0.f, 0.f, 0.f};
    #pragma unroll
    for (int ks = 0; ks < 8; ++ks) {
        bf16x8 a = *(const bf16x8*)(Ap + ks * 32);
        bf16x8 b0 = *(const bf16x8*)(Bp + ks * 32);
        bf16x8 b1 = *(const bf16x8*)(Bp + 16 * DIN + ks * 32);
        acc[0] = __builtin_amdgcn_mfma_f32_16x16x32_bf16(a, b0, acc[0], 0, 0, 0);
        acc[1] = __builtin_amdgcn_mfma_f32_16x16x32_bf16(a, b1, acc[1], 0, 0, 0);
    }
    int rowb = r0 + ((lane >> 4) << 2);
    #pragma unroll
    for (int nf = 0; nf < 2; ++nf) {
        int col = c0 + nf * 16 + (lane & 15);
        float bb = b_in[col];
        #pragma unroll
        for (int j = 0; j < 4; ++j)
            hb[(size_t)(rowb + j) * H + col] = f2bf(acc[nf][j] + bb);
    }
}

// ------ qkvs MFMA: k -> ko (bf16), q/v -> interleaved qv, self -> agg (f32) ------
__global__ __launch_bounds__(256) void k_qkvs_mfma(const ushort_t* __restrict__ hb,
                                                   const ushort_t* __restrict__ Bq, // [512][128]
                                                   const float* __restrict__ bk, const float* __restrict__ bq,
                                                   const float* __restrict__ bv, const float* __restrict__ bs,
                                                   ushort_t* __restrict__ ko, ushort_t* __restrict__ qv,
                                                   float* __restrict__ agg)
{
    int gw = blockIdx.x * 4 + (threadIdx.x >> 6);
    int lane = threadIdx.x & 63;
    int rg = gw >> 3, cg = gw & 7;
    int r0 = rg * 16, c0 = cg * 64;
    const ushort_t* Ap = hb + (size_t)(r0 + (lane & 15)) * H + 8 * (lane >> 4);
    const ushort_t* Bp = Bq + (size_t)(c0 + (lane & 15)) * H + 8 * (lane >> 4);
    f32x4 acc[4];
    #pragma unroll
    for (int nf = 0; nf < 4; ++nf) acc[nf] = (f32x4){0.f, 0.f, 0.f, 0.f};
    #pragma unroll
    for (int ks = 0; ks < 4; ++ks) {
        bf16x8 a = *(const bf16x8*)(Ap + ks * 32);
        #pragma unroll
        for (int nf = 0; nf < 4; ++nf) {
            bf16x8 b = *(const bf16x8*)(Bp + nf * 16 * H + ks * 32);
            acc[nf] = __builtin_amdgcn_mfma_f32_16x16x32_bf16(a, b, acc[nf], 0, 0, 0);
        }
    }
    int mat = cg >> 1;                     // 0=k,1=q,2=v,3=self
    int rowb = r0 + ((lane >> 4) << 2);
    const float* bias = (mat == 0) ? bk : (mat == 1) ? bq : (mat == 2) ? bv : bs;
    if (mat == 0) {
        #pragma unroll
        for (int nf = 0; nf < 4; ++nf) {
            int col = ((cg & 1) << 6) + nf * 16 + (lane & 15);
            float bb = bias[col];
            #pragma unroll
            for (int j = 0; j < 4; ++j)
                ko[(size_t)(rowb + j) * H + col] = f2bf(acc[nf][j] + bb);
        }
    } else if (mat < 3) {
        int voff = (mat == 2) ? 2 : 0;     // q at ushorts 0..1, v at 2..3
        #pragma unroll
        for (int nf = 0; nf < 4; ++nf) {
            int col = ((cg & 1) << 6) + nf * 16 + (lane & 15);
            float bb = bias[col];
            int ent = ((col >> 1) << 2) + (col & 1) + voff;
            #pragma unroll
            for (int j = 0; j < 4; ++j)
                qv[(size_t)(rowb + j) * 256 + ent] = f2bf(acc[nf][j] + bb);
        }
    } else {
        #pragma unroll
        for (int nf = 0; nf < 4; ++nf) {
            int col = ((cg & 1) << 6) + nf * 16 + (lane & 15);
            float bb = bias[col];
            #pragma unroll
            for (int j = 0; j < 4; ++j)
                agg[(size_t)(rowb + j) * H + col] = acc[nf][j] + bb;
        }
    }
}

// ================= CSR build =================
__global__ __launch_bounds__(256) void k_hist(const int* __restrict__ ei, int* __restrict__ deg)
{
    int e = blockIdx.x * 256 + threadIdx.x;
    int dst = ei[E_EDGES + e];
    atomicAdd(&deg[dst], 1);
}

// phase 1: per-block sums of deg
__global__ __launch_bounds__(256) void k_bsum(const int* __restrict__ deg, int* __restrict__ bsum)
{
    __shared__ int ws[4];
    int t = threadIdx.x;
    int i = blockIdx.x * 256 + t;
    int v = (i < N_NODES) ? deg[i] : 0;
    #pragma unroll
    for (int off = 32; off > 0; off >>= 1) v += __shfl_down(v, off);
    if ((t & 63) == 0) ws[t >> 6] = v;
    __syncthreads();
    if (t == 0) bsum[blockIdx.x] = ws[0] + ws[1] + ws[2] + ws[3];
}

// phase 2: exclusive scan of 196 block sums (one block)
__global__ __launch_bounds__(256) void k_bscan(const int* __restrict__ bsum, int* __restrict__ boff)
{
    __shared__ int ws[4];
    int t = threadIdx.x;
    int v = (t < NBLK) ? bsum[t] : 0;
    int lane = t & 63, wid = t >> 6;
    int inc = v;
    #pragma unroll
    for (int off = 1; off < 64; off <<= 1) {
        int u = __shfl_up(inc, off);
        if (lane >= off) inc += u;
    }
    if (lane == 63) ws[wid] = inc;
    __syncthreads();
    if (t == 0) {
        int s = 0;
        #pragma unroll
        for (int w = 0; w < 4; ++w) { int x = ws[w]; ws[w] = s; s += x; }
    }
    __syncthreads();
    if (t < NBLK) boff[t] = inc - v + ws[wid];
}

// phase 3: block-local exclusive scan + block offset -> rowptr
__global__ __launch_bounds__(256) void k_rowptr(const int* __restrict__ deg,
                                                const int* __restrict__ boff,
                                                int* __restrict__ rowptr)
{
    __shared__ int ws[4];
    int t = threadIdx.x;
    int i = blockIdx.x * 256 + t;
    int v = (i < N_NODES) ? deg[i] : 0;
    int lane = t & 63, wid = t >> 6;
    int inc = v;
    #pragma unroll
    for (int off = 1; off < 64; off <<= 1) {
        int u = __shfl_up(inc, off);
        if (lane >= off) inc += u;
    }
    if (lane == 63) ws[wid] = inc;
    __syncthreads();
    if (t == 0) {
        int s = 0;
        #pragma unroll
        for (int w = 0; w < 4; ++w) { int x = ws[w]; ws[w] = s; s += x; }
    }
    __syncthreads();
    int excl = inc - v + ws[wid] + boff[blockIdx.x];
    if (i < N_NODES) rowptr[i] = excl;
    if (i == N_NODES - 1) rowptr[N_NODES] = excl + v;
}

__global__ __launch_bounds__(256) void k_scatter(const int* __restrict__ ei,
                                                 const float* __restrict__ ea,
                                                 const int* __restrict__ rowptr,
                                                 int* __restrict__ fill,
                                                 uint2* __restrict__ csr)
{
    int e = blockIdx.x * 256 + threadIdx.x;
    int src = ei[e];
    int dst = ei[E_EDGES + e];
    int pos = rowptr[dst] + atomicAdd(&fill[dst], 1);
    csr[pos] = make_uint2((uint_t)src, __float_as_uint(ea[e]));
}

// ===== aggregation (one wave per dst node) + LayerNorm + GELU -> h (bf16) =====
__global__ __launch_bounds__(256) void k_agg_ln(const int* __restrict__ rowptr,
                                                const uint2* __restrict__ csr,
                                                const ushort_t* __restrict__ ko,
                                                const uint2* __restrict__ qvp,
                                                const float* __restrict__ aggin,
                                                const float* __restrict__ We,
                                                const float* __restrict__ be,
                                                const float* __restrict__ gamma,
                                                const float* __restrict__ beta,
                                                ushort_t* __restrict__ hout)
{
    int tid = threadIdx.x;
    int lane = tid & 63;
    int node = blockIdx.x * 4 + (tid >> 6);
    int j = lane * 2;

    float2 we  = *(const float2*)(We + j);
    float2 bev = *(const float2*)(be + j);
    uint_t kdu = ((const uint_t*)ko)[(size_t)node * 64 + lane];
    float kdx = bf2f(kdu & 0xffffu), kdy = bf2f(kdu >> 16);
    float2 acc = ((const float2*)aggin)[(size_t)node * 64 + lane]; // h@Ws + b_gcn
    int p = rowptr[node];
    int pend = rowptr[node + 1];

#define EDGE(c, u) {                                                          \
    float a  = __uint_as_float((c).y);                                        \
    float qx = bf2f((u).x & 0xffffu), qy = bf2f((u).x >> 16);                 \
    float vx = bf2f((u).y & 0xffffu), vy = bf2f((u).y >> 16);                 \
    float ex = fmaf(a, we.x, bev.x), ey = fmaf(a, we.y, bev.y);               \
    float gx = kdx + qx + 2.f * ex,  gy = kdy + qy + 2.f * ey;                \
    float sx = __builtin_amdgcn_rcpf(1.f + __expf(-gx));                      \
    float sy = __builtin_amdgcn_rcpf(1.f + __expf(-gy));                      \
    acc.x = fmaf(sx, vx + ex, acc.x);                                         \
    acc.y = fmaf(sy, vy + ey, acc.y); }

    for (; p + 4 <= pend; p += 4) {
        uint2 c0 = csr[p], c1 = csr[p + 1], c2 = csr[p + 2], c3 = csr[p + 3];
        uint2 u0 = qvp[c0.x * 64u + lane];
        uint2 u1 = qvp[c1.x * 64u + lane];
        uint2 u2 = qvp[c2.x * 64u + lane];
        uint2 u3 = qvp[c3.x * 64u + lane];
        EDGE(c0, u0); EDGE(c1, u1); EDGE(c2, u2); EDGE(c3, u3);
    }
    for (; p < pend; ++p) {
        uint2 c = csr[p];
        uint2 u = qvp[c.x * 64u + lane];
        EDGE(c, u);
    }
#undef EDGE

    float s  = acc.x + acc.y;
    float s2 = acc.x * acc.x + acc.y * acc.y;
    #pragma unroll
    for (int off = 32; off > 0; off >>= 1) {
        s  += __shfl_down(s, off);
        s2 += __shfl_down(s2, off);
    }
    s  = __shfl(s, 0);
    s2 = __shfl(s2, 0);
    float mu  = s * (1.f / H);
    float var = s2 * (1.f / H) - mu * mu;
    float rstd = rsqrtf(var + EPSF);
    float2 g = *(const float2*)(gamma + j);
    float2 b = *(const float2*)(beta + j);
    float y0 = (acc.x - mu) * rstd * g.x + b.x;
    float y1 = (acc.y - mu) * rstd * g.y + b.y;
    y0 = 0.5f * y0 * (1.f + erff(y0 * 0.70710678118f));
    y1 = 0.5f * y1 * (1.f + erff(y1 * 0.70710678118f));
    uint_t packed = ((uint_t)f2bf(y1) << 16) | (uint_t)f2bf(y0);
    ((uint_t*)hout)[(size_t)node * 64 + lane] = packed;
}

// ---------------- out_proj MFMA: out = h @ W_out (fp32 out) ----------------
__global__ __launch_bounds__(256) void k_out_mfma(const ushort_t* __restrict__ hb,
                                                  const ushort_t* __restrict__ Bout, // [64][128]
                                                  float* __restrict__ out)
{
    int gw = blockIdx.x * 4 + (threadIdx.x >> 6);
    if (gw >= 6250) return;
    int lane = threadIdx.x & 63;
    int rg = gw >> 1, cg = gw & 1;
    int r0 = rg * 16, c0 = cg * 32;
    const ushort_t* Ap = hb + (size_t)(r0 + (lane & 15)) * H + 8 * (lane >> 4);
    const ushort_t* Bp = Bout + (size_t)(c0 + (lane & 15)) * H + 8 * (lane >> 4);
    f32x4 acc[2];
    acc[0] = (f32x4){0.f, 0.f, 0.f, 0.f};
    acc[1] = (f32x4){0.f, 0.f, 0.f, 0.f};
    #pragma unroll
    for (int ks = 0; ks < 4; ++ks) {
        bf16x8 a = *(const bf16x8*)(Ap + ks * 32);
        bf16x8 b0 = *(const bf16x8*)(Bp + ks * 32);
        bf16x8 b1 = *(const bf16x8*)(Bp + 16 * H + ks * 32);
        acc[0] = __builtin_amdgcn_mfma_f32_16x16x32_bf16(a, b0, acc[0], 0, 0, 0);
        acc[1] = __builtin_amdgcn_mfma_f32_16x16x32_bf16(a, b1, acc[1], 0, 0, 0);
    }
    int rowb = r0 + ((lane >> 4) << 2);
    #pragma unroll
    for (int nf = 0; nf < 2; ++nf) {
        int col = c0 + nf * 16 + (lane & 15);
        #pragma unroll
        for (int j = 0; j < 4; ++j)
            out[(size_t)(rowb + j) * DOUT + col] = acc[nf][j];
    }
}

extern "C" void kernel_launch(void* const* d_in, const int* in_sizes, int n_in,
                              void* d_out, int out_size, void* d_ws, size_t ws_size,
                              hipStream_t stream) {
    const float* x         = (const float*)d_in[0];
    const float* edge_attr = (const float*)d_in[1];
    const float* W_in      = (const float*)d_in[2];
    const float* b_in      = (const float*)d_in[3];
    const float* Wk        = (const float*)d_in[4];
    const float* bk        = (const float*)d_in[5];
    const float* Wq        = (const float*)d_in[6];
    const float* bq        = (const float*)d_in[7];
    const float* Wv        = (const float*)d_in[8];
    const float* bv        = (const float*)d_in[9];
    const float* We        = (const float*)d_in[10];
    const float* be        = (const float*)d_in[11];
    const float* Ws        = (const float*)d_in[12];
    const float* b_gcn     = (const float*)d_in[13];
    const float* gamma     = (const float*)d_in[14];
    const float* beta      = (const float*)d_in[15];
    const float* W_out     = (const float*)d_in[16];
    const int*   edge_index= (const int*)d_in[17];
    float* out = (float*)d_out;

    char* wsb = (char*)d_ws;
    const size_t NH2 = (size_t)N_NODES * H * 2;
    ushort_t* hb  = (ushort_t*)wsb;                  wsb += NH2;
    ushort_t* ko  = (ushort_t*)wsb;                  wsb += NH2;
    ushort_t* qv  = (ushort_t*)wsb;                  wsb += (size_t)N_NODES * 512;
    float*    agg = (float*)wsb;                     wsb += (size_t)N_NODES * H * 4;
    ushort_t* xb  = (ushort_t*)wsb;                  wsb += (size_t)N_NODES * DIN * 2;
    ushort_t* Bq  = (ushort_t*)wsb;                  wsb += 3 * 512 * 128 * 2;
    ushort_t* Bin = (ushort_t*)wsb;                  wsb += 128 * 256 * 2;
    ushort_t* Bout= (ushort_t*)wsb;                  wsb += 64 * 128 * 2;
    uint2* csr    = (uint2*)wsb;                     wsb += (size_t)E_EDGES * 8;
    int*   deg    = (int*)wsb;                       wsb += N_NODES * 4;
    int*   fill   = (int*)wsb;                       wsb += N_NODES * 4;
    int*   rowptr = (int*)wsb;                       wsb += (N_NODES + 1) * 4;
    int*   bsum   = (int*)wsb;                       wsb += NBLK * 4;
    int*   boff   = (int*)wsb;                       wsb += NBLK * 4;

    // CSR build (edge_index constant across layers)
    hipMemsetAsync(deg, 0, 2 * N_NODES * sizeof(int), stream); // zeroes deg + fill
    k_hist<<<E_EDGES / 256, 256, 0, stream>>>(edge_index, deg);
    k_bsum<<<NBLK, 256, 0, stream>>>(deg, bsum);
    k_bscan<<<1, 256, 0, stream>>>(bsum, boff);
    k_rowptr<<<NBLK, 256, 0, stream>>>(deg, boff, rowptr);
    k_scatter<<<E_EDGES / 256, 256, 0, stream>>>(edge_index, edge_attr, rowptr, fill, csr);

    // conversions + weight packing
    k_convx<<<(N_NODES * DIN / 4 + 255) / 256, 256, 0, stream>>>(x, xb);
    k_pack<<<928, 256, 0, stream>>>(Wk, Wq, Wv, Ws, W_in, W_out, Bq, Bin, Bout);

    k_in_mfma<<<3125, 256, 0, stream>>>(xb, Bin, b_in, hb);
    for (int l = 0; l < 3; ++l) {
        k_qkvs_mfma<<<6250, 256, 0, stream>>>(hb, Bq + (size_t)l * 512 * 128,
                                              bk + l * H, bq + l * H, bv + l * H, b_gcn + l * H,
                                              ko, qv, agg);
        k_agg_ln<<<N_NODES / 4, 256, 0, stream>>>(rowptr, csr, ko, (const uint2*)qv, agg,
                                                  We + l * H, be + l * H,
                                                  gamma + l * H, beta + l * H, hb);
    }
    k_out_mfma<<<1563, 256, 0, stream>>>(hb, Bout, out);
}

// Round 6
// 468.175 us; speedup vs baseline: 5.4141x; 1.1418x over previous
//
#include <hip/hip_runtime.h>

#define N_NODES 50000
#define NPAD    50048   // padded row count (multiple of 64) so 32-row tiles need no guard
#define E_EDGES 800000
#define DIN 256
#define H 128
#define DOUT 64
#define EPSF 1e-5f
#define NBLK 196   // ceil(N_NODES/256)
#define RT   1563  // ceil(N_NODES/32) row tiles

typedef __bf16 bf16x8 __attribute__((ext_vector_type(8)));
typedef float  f32x4  __attribute__((ext_vector_type(4)));
typedef unsigned short ushort_t;
typedef unsigned int   uint_t;

__device__ inline float bf2f(uint_t u) {
    union { uint_t i; float f; } v; v.i = u << 16; return v.f;
}
__device__ inline ushort_t f2bf(float f) {
    uint_t u = __float_as_uint(f);
    uint_t r = (u + 0x7fffu + ((u >> 16) & 1u)) >> 16;
    return (ushort_t)r;
}

// ---------------- x -> bf16 ----------------
__global__ __launch_bounds__(256) void k_convx(const float* __restrict__ x, ushort_t* __restrict__ xb)
{
    int i = blockIdx.x * 256 + threadIdx.x;
    float4 v = ((const float4*)x)[i];
    ushort4 o;
    o.x = f2bf(v.x); o.y = f2bf(v.y); o.z = f2bf(v.z); o.w = f2bf(v.w);
    ((ushort4*)xb)[i] = o;
}

// ----------- merged weight packing (B^T layouts) -----------
__global__ __launch_bounds__(256) void k_pack(const float* __restrict__ Wk, const float* __restrict__ Wq,
                                              const float* __restrict__ Wv, const float* __restrict__ Ws,
                                              const float* __restrict__ W_in, const float* __restrict__ W_out,
                                              ushort_t* __restrict__ Bq, ushort_t* __restrict__ Bin,
                                              ushort_t* __restrict__ Bout)
{
    int t = blockIdx.x * 256 + threadIdx.x;
    if (t < 196608) {
        int l = t >> 16;
        int r = t & 65535;
        int c = r >> 7;
        int k = r & 127;
        int m = c >> 7;
        int cm = c & 127;
        const float* W = (m == 0) ? Wk : (m == 1) ? Wq : (m == 2) ? Wv : Ws;
        Bq[t] = f2bf(W[(size_t)l * H * H + k * H + cm]);
    } else if (t < 229376) {
        int t2 = t - 196608;
        int c = t2 >> 8;
        int k = t2 & 255;
        Bin[t2] = f2bf(W_in[k * H + c]);
    } else {
        int t3 = t - 229376;
        int c = t3 >> 7;
        int k = t3 & 127;
        Bout[t3] = f2bf(W_out[k * DOUT + c]);
    }
}

// ---------------- in_proj MFMA: h = bf16(x @ W_in + b_in) ----------------
// wave: 32 rows x 32 cols, K=256. waves = RT*4 = 6252, blocks = 1563.
__global__ __launch_bounds__(256) void k_in_mfma(const ushort_t* __restrict__ xb,
                                                 const ushort_t* __restrict__ Bin,
                                                 const float* __restrict__ b_in,
                                                 ushort_t* __restrict__ hb)
{
    int gw = blockIdx.x * 4 + (threadIdx.x >> 6);
    int lane = threadIdx.x & 63;
    int rt = gw >> 2, c32 = (gw & 3) * 32;
    int r0 = rt * 32;
    const ushort_t* Ap = xb + (size_t)(r0 + (lane & 15)) * DIN + 8 * (lane >> 4);
    const ushort_t* Bp = Bin + (size_t)(c32 + (lane & 15)) * DIN + 8 * (lane >> 4);
    f32x4 acc[2][2]; // [rb][nf]
    #pragma unroll
    for (int rb = 0; rb < 2; ++rb)
        #pragma unroll
        for (int nf = 0; nf < 2; ++nf) acc[rb][nf] = (f32x4){0.f, 0.f, 0.f, 0.f};
    #pragma unroll
    for (int ks = 0; ks < 8; ++ks) {
        bf16x8 a0 = *(const bf16x8*)(Ap + ks * 32);
        bf16x8 a1 = *(const bf16x8*)(Ap + 16 * DIN + ks * 32);
        bf16x8 b0 = *(const bf16x8*)(Bp + ks * 32);
        bf16x8 b1 = *(const bf16x8*)(Bp + 16 * DIN + ks * 32);
        acc[0][0] = __builtin_amdgcn_mfma_f32_16x16x32_bf16(a0, b0, acc[0][0], 0, 0, 0);
        acc[1][0] = __builtin_amdgcn_mfma_f32_16x16x32_bf16(a1, b0, acc[1][0], 0, 0, 0);
        acc[0][1] = __builtin_amdgcn_mfma_f32_16x16x32_bf16(a0, b1, acc[0][1], 0, 0, 0);
        acc[1][1] = __builtin_amdgcn_mfma_f32_16x16x32_bf16(a1, b1, acc[1][1], 0, 0, 0);
    }
    int rowoff = (lane >> 4) << 2;
    #pragma unroll
    for (int nf = 0; nf < 2; ++nf) {
        int col = c32 + nf * 16 + (lane & 15);
        float bb = b_in[col];
        #pragma unroll
        for (int rb = 0; rb < 2; ++rb)
            #pragma unroll
            for (int j = 0; j < 4; ++j)
                hb[(size_t)(r0 + rb * 16 + rowoff + j) * H + col] = f2bf(acc[rb][nf][j] + bb);
    }
}

// ------ qkvs MFMA: pair 0 -> packed qv uint{q,v}; pair 1 -> ko (bf16) + agg (f32) ------
// wave: 32 rows x 32 cols x 2 matrices. waves = RT*8 = 12504, blocks = 3126.
__global__ __launch_bounds__(256) void k_qkvs_mfma(const ushort_t* __restrict__ hb,
                                                   const ushort_t* __restrict__ Bq, // [512][128]
                                                   const float* __restrict__ bk, const float* __restrict__ bq,
                                                   const float* __restrict__ bv, const float* __restrict__ bs,
                                                   ushort_t* __restrict__ ko, uint_t* __restrict__ qv,
                                                   float* __restrict__ agg)
{
    int gw = blockIdx.x * 4 + (threadIdx.x >> 6);
    int lane = threadIdx.x & 63;
    int rt = gw >> 3, cfg = gw & 7;
    int pair = cfg >> 2, c32 = (cfg & 3) * 32;
    int r0 = rt * 32;
    const ushort_t* Ap = hb + (size_t)(r0 + (lane & 15)) * H + 8 * (lane >> 4);
    int cb0 = pair ? 0   : 128;   // k : q
    int cb1 = pair ? 384 : 256;   // s : v
    const ushort_t* Bp0 = Bq + (size_t)(cb0 + c32 + (lane & 15)) * H + 8 * (lane >> 4);
    const ushort_t* Bp1 = Bq + (size_t)(cb1 + c32 + (lane & 15)) * H + 8 * (lane >> 4);
    f32x4 acc[2][2][2]; // [rb][mat][nf]
    #pragma unroll
    for (int rb = 0; rb < 2; ++rb)
        #pragma unroll
        for (int m = 0; m < 2; ++m)
            #pragma unroll
            for (int nf = 0; nf < 2; ++nf) acc[rb][m][nf] = (f32x4){0.f, 0.f, 0.f, 0.f};
    #pragma unroll
    for (int ks = 0; ks < 4; ++ks) {
        bf16x8 a0 = *(const bf16x8*)(Ap + ks * 32);
        bf16x8 a1 = *(const bf16x8*)(Ap + 16 * H + ks * 32);
        #pragma unroll
        for (int nf = 0; nf < 2; ++nf) {
            bf16x8 b0 = *(const bf16x8*)(Bp0 + nf * 16 * H + ks * 32);
            bf16x8 b1 = *(const bf16x8*)(Bp1 + nf * 16 * H + ks * 32);
            acc[0][0][nf] = __builtin_amdgcn_mfma_f32_16x16x32_bf16(a0, b0, acc[0][0][nf], 0, 0, 0);
            acc[1][0][nf] = __builtin_amdgcn_mfma_f32_16x16x32_bf16(a1, b0, acc[1][0][nf], 0, 0, 0);
            acc[0][1][nf] = __builtin_amdgcn_mfma_f32_16x16x32_bf16(a0, b1, acc[0][1][nf], 0, 0, 0);
            acc[1][1][nf] = __builtin_amdgcn_mfma_f32_16x16x32_bf16(a1, b1, acc[1][1][nf], 0, 0, 0);
        }
    }
    int rowoff = (lane >> 4) << 2;
    if (pair == 0) {
        #pragma unroll
        for (int nf = 0; nf < 2; ++nf) {
            int col = c32 + nf * 16 + (lane & 15);
            float bbq = bq[col], bbv = bv[col];
            #pragma unroll
            for (int rb = 0; rb < 2; ++rb)
                #pragma unroll
                for (int j = 0; j < 4; ++j) {
                    size_t row = r0 + rb * 16 + rowoff + j;
                    uint_t qb = f2bf(acc[rb][0][nf][j] + bbq);
                    uint_t vb = f2bf(acc[rb][1][nf][j] + bbv);
                    qv[row * H + col] = (vb << 16) | qb;
                }
        }
    } else {
        #pragma unroll
        for (int nf = 0; nf < 2; ++nf) {
            int col = c32 + nf * 16 + (lane & 15);
            float bbk = bk[col], bbs = bs[col];
            #pragma unroll
            for (int rb = 0; rb < 2; ++rb)
                #pragma unroll
                for (int j = 0; j < 4; ++j) {
                    size_t row = r0 + rb * 16 + rowoff + j;
                    ko[row * H + col]  = f2bf(acc[rb][0][nf][j] + bbk);
                    agg[row * H + col] = acc[rb][1][nf][j] + bbs;
                }
        }
    }
}

// ================= CSR build =================
__global__ __launch_bounds__(256) void k_hist(const int* __restrict__ ei, int* __restrict__ deg)
{
    int e = blockIdx.x * 256 + threadIdx.x;
    int dst = ei[E_EDGES + e];
    atomicAdd(&deg[dst], 1);
}

__global__ __launch_bounds__(256) void k_bsum(const int* __restrict__ deg, int* __restrict__ bsum)
{
    __shared__ int ws[4];
    int t = threadIdx.x;
    int i = blockIdx.x * 256 + t;
    int v = (i < N_NODES) ? deg[i] : 0;
    #pragma unroll
    for (int off = 32; off > 0; off >>= 1) v += __shfl_down(v, off);
    if ((t & 63) == 0) ws[t >> 6] = v;
    __syncthreads();
    if (t == 0) bsum[blockIdx.x] = ws[0] + ws[1] + ws[2] + ws[3];
}

__global__ __launch_bounds__(256) void k_bscan(const int* __restrict__ bsum, int* __restrict__ boff)
{
    __shared__ int ws[4];
    int t = threadIdx.x;
    int v = (t < NBLK) ? bsum[t] : 0;
    int lane = t & 63, wid = t >> 6;
    int inc = v;
    #pragma unroll
    for (int off = 1; off < 64; off <<= 1) {
        int u = __shfl_up(inc, off);
        if (lane >= off) inc += u;
    }
    if (lane == 63) ws[wid] = inc;
    __syncthreads();
    if (t == 0) {
        int s = 0;
        #pragma unroll
        for (int w = 0; w < 4; ++w) { int x = ws[w]; ws[w] = s; s += x; }
    }
    __syncthreads();
    if (t < NBLK) boff[t] = inc - v + ws[wid];
}

__global__ __launch_bounds__(256) void k_rowptr(const int* __restrict__ deg,
                                                const int* __restrict__ boff,
                                                int* __restrict__ rowptr)
{
    __shared__ int ws[4];
    int t = threadIdx.x;
    int i = blockIdx.x * 256 + t;
    int v = (i < N_NODES) ? deg[i] : 0;
    int lane = t & 63, wid = t >> 6;
    int inc = v;
    #pragma unroll
    for (int off = 1; off < 64; off <<= 1) {
        int u = __shfl_up(inc, off);
        if (lane >= off) inc += u;
    }
    if (lane == 63) ws[wid] = inc;
    __syncthreads();
    if (t == 0) {
        int s = 0;
        #pragma unroll
        for (int w = 0; w < 4; ++w) { int x = ws[w]; ws[w] = s; s += x; }
    }
    __syncthreads();
    int excl = inc - v + ws[wid] + boff[blockIdx.x];
    if (i < N_NODES) rowptr[i] = excl;
    if (i == N_NODES - 1) rowptr[N_NODES] = excl + v;
}

__global__ __launch_bounds__(256) void k_scatter(const int* __restrict__ ei,
                                                 const float* __restrict__ ea,
                                                 const int* __restrict__ rowptr,
                                                 int* __restrict__ fill,
                                                 uint2* __restrict__ csr)
{
    int e = blockIdx.x * 256 + threadIdx.x;
    int src = ei[e];
    int dst = ei[E_EDGES + e];
    int pos = rowptr[dst] + atomicAdd(&fill[dst], 1);
    csr[pos] = make_uint2((uint_t)src, __float_as_uint(ea[e]));
}

// ===== aggregation (one wave per dst node) + LayerNorm + GELU -> h (bf16) =====
__global__ __launch_bounds__(256) void k_agg_ln(const int* __restrict__ rowptr,
                                                const uint2* __restrict__ csr,
                                                const ushort_t* __restrict__ ko,
                                                const uint2* __restrict__ qvp,  // uint{q,v} per col, viewed as uint2
                                                const float* __restrict__ aggin,
                                                const float* __restrict__ We,
                                                const float* __restrict__ be,
                                                const float* __restrict__ gamma,
                                                const float* __restrict__ beta,
                                                ushort_t* __restrict__ hout)
{
    int tid = threadIdx.x;
    int lane = tid & 63;
    int node = blockIdx.x * 4 + (tid >> 6);
    int j = lane * 2;

    float2 we  = *(const float2*)(We + j);
    float2 bev = *(const float2*)(be + j);
    uint_t kdu = ((const uint_t*)ko)[(size_t)node * 64 + lane];
    float kdx = bf2f(kdu & 0xffffu), kdy = bf2f(kdu >> 16);
    float2 acc = ((const float2*)aggin)[(size_t)node * 64 + lane]; // h@Ws + b_gcn
    int p = rowptr[node];
    int pend = rowptr[node + 1];

#define EDGE(c, u) {                                                          \
    float a  = __uint_as_float((c).y);                                        \
    float qx = bf2f((u).x & 0xffffu), vx = bf2f((u).x >> 16);                 \
    float qy = bf2f((u).y & 0xffffu), vy = bf2f((u).y >> 16);                 \
    float ex = fmaf(a, we.x, bev.x), ey = fmaf(a, we.y, bev.y);               \
    float gx = kdx + qx + 2.f * ex,  gy = kdy + qy + 2.f * ey;                \
    float sx = __builtin_amdgcn_rcpf(1.f + __expf(-gx));                      \
    float sy = __builtin_amdgcn_rcpf(1.f + __expf(-gy));                      \
    acc.x = fmaf(sx, vx + ex, acc.x);                                         \
    acc.y = fmaf(sy, vy + ey, acc.y); }

    for (; p + 4 <= pend; p += 4) {
        uint2 c0 = csr[p], c1 = csr[p + 1], c2 = csr[p + 2], c3 = csr[p + 3];
        uint2 u0 = qvp[c0.x * 64u + lane];
        uint2 u1 = qvp[c1.x * 64u + lane];
        uint2 u2 = qvp[c2.x * 64u + lane];
        uint2 u3 = qvp[c3.x * 64u + lane];
        EDGE(c0, u0); EDGE(c1, u1); EDGE(c2, u2); EDGE(c3, u3);
    }
    for (; p < pend; ++p) {
        uint2 c = csr[p];
        uint2 u = qvp[c.x * 64u + lane];
        EDGE(c, u);
    }
#undef EDGE

    float s  = acc.x + acc.y;
    float s2 = acc.x * acc.x + acc.y * acc.y;
    #pragma unroll
    for (int off = 32; off > 0; off >>= 1) {
        s  += __shfl_down(s, off);
        s2 += __shfl_down(s2, off);
    }
    s  = __shfl(s, 0);
    s2 = __shfl(s2, 0);
    float mu  = s * (1.f / H);
    float var = s2 * (1.f / H) - mu * mu;
    float rstd = rsqrtf(var + EPSF);
    float2 g = *(const float2*)(gamma + j);
    float2 b = *(const float2*)(beta + j);
    float y0 = (acc.x - mu) * rstd * g.x + b.x;
    float y1 = (acc.y - mu) * rstd * g.y + b.y;
    y0 = 0.5f * y0 * (1.f + erff(y0 * 0.70710678118f));
    y1 = 0.5f * y1 * (1.f + erff(y1 * 0.70710678118f));
    uint_t packed = ((uint_t)f2bf(y1) << 16) | (uint_t)f2bf(y0);
    ((uint_t*)hout)[(size_t)node * 64 + lane] = packed;
}

// ---------------- out_proj MFMA: out = h @ W_out (fp32 out) ----------------
__global__ __launch_bounds__(256) void k_out_mfma(const ushort_t* __restrict__ hb,
                                                  const ushort_t* __restrict__ Bout, // [64][128]
                                                  float* __restrict__ out)
{
    int gw = blockIdx.x * 4 + (threadIdx.x >> 6);
    if (gw >= 6250) return;
    int lane = threadIdx.x & 63;
    int rg = gw >> 1, cg = gw & 1;
    int r0 = rg * 16, c0 = cg * 32;
    const ushort_t* Ap = hb + (size_t)(r0 + (lane & 15)) * H + 8 * (lane >> 4);
    const ushort_t* Bp = Bout + (size_t)(c0 + (lane & 15)) * H + 8 * (lane >> 4);
    f32x4 acc[2];
    acc[0] = (f32x4){0.f, 0.f, 0.f, 0.f};
    acc[1] = (f32x4){0.f, 0.f, 0.f, 0.f};
    #pragma unroll
    for (int ks = 0; ks < 4; ++ks) {
        bf16x8 a = *(const bf16x8*)(Ap + ks * 32);
        bf16x8 b0 = *(const bf16x8*)(Bp + ks * 32);
        bf16x8 b1 = *(const bf16x8*)(Bp + 16 * H + ks * 32);
        acc[0] = __builtin_amdgcn_mfma_f32_16x16x32_bf16(a, b0, acc[0], 0, 0, 0);
        acc[1] = __builtin_amdgcn_mfma_f32_16x16x32_bf16(a, b1, acc[1], 0, 0, 0);
    }
    int rowb = r0 + ((lane >> 4) << 2);
    #pragma unroll
    for (int nf = 0; nf < 2; ++nf) {
        int col = c0 + nf * 16 + (lane & 15);
        #pragma unroll
        for (int j = 0; j < 4; ++j)
            out[(size_t)(rowb + j) * DOUT + col] = acc[nf][j];
    }
}

extern "C" void kernel_launch(void* const* d_in, const int* in_sizes, int n_in,
                              void* d_out, int out_size, void* d_ws, size_t ws_size,
                              hipStream_t stream) {
    const float* x         = (const float*)d_in[0];
    const float* edge_attr = (const float*)d_in[1];
    const float* W_in      = (const float*)d_in[2];
    const float* b_in      = (const float*)d_in[3];
    const float* Wk        = (const float*)d_in[4];
    const float* bk        = (const float*)d_in[5];
    const float* Wq        = (const float*)d_in[6];
    const float* bq        = (const float*)d_in[7];
    const float* Wv        = (const float*)d_in[8];
    const float* bv        = (const float*)d_in[9];
    const float* We        = (const float*)d_in[10];
    const float* be        = (const float*)d_in[11];
    const float* Ws        = (const float*)d_in[12];
    const float* b_gcn     = (const float*)d_in[13];
    const float* gamma     = (const float*)d_in[14];
    const float* beta      = (const float*)d_in[15];
    const float* W_out     = (const float*)d_in[16];
    const int*   edge_index= (const int*)d_in[17];
    float* out = (float*)d_out;

    char* wsb = (char*)d_ws;
    ushort_t* hb  = (ushort_t*)wsb;                  wsb += (size_t)NPAD * H * 2;
    ushort_t* ko  = (ushort_t*)wsb;                  wsb += (size_t)NPAD * H * 2;
    uint_t*   qv  = (uint_t*)wsb;                    wsb += (size_t)NPAD * H * 4;
    float*    agg = (float*)wsb;                     wsb += (size_t)NPAD * H * 4;
    ushort_t* xb  = (ushort_t*)wsb;                  wsb += (size_t)NPAD * DIN * 2;
    ushort_t* Bq  = (ushort_t*)wsb;                  wsb += 3 * 512 * 128 * 2;
    ushort_t* Bin = (ushort_t*)wsb;                  wsb += 128 * 256 * 2;
    ushort_t* Bout= (ushort_t*)wsb;                  wsb += 64 * 128 * 2;
    uint2* csr    = (uint2*)wsb;                     wsb += (size_t)E_EDGES * 8;
    int*   deg    = (int*)wsb;                       wsb += N_NODES * 4;
    int*   fill   = (int*)wsb;                       wsb += N_NODES * 4;
    int*   rowptr = (int*)wsb;                       wsb += (N_NODES + 1) * 4;
    int*   bsum   = (int*)wsb;                       wsb += NBLK * 4;
    int*   boff   = (int*)wsb;                       wsb += NBLK * 4;

    // CSR build (edge_index constant across layers)
    hipMemsetAsync(deg, 0, 2 * N_NODES * sizeof(int), stream); // zeroes deg + fill
    k_hist<<<E_EDGES / 256, 256, 0, stream>>>(edge_index, deg);
    k_bsum<<<NBLK, 256, 0, stream>>>(deg, bsum);
    k_bscan<<<1, 256, 0, stream>>>(bsum, boff);
    k_rowptr<<<NBLK, 256, 0, stream>>>(deg, boff, rowptr);
    k_scatter<<<E_EDGES / 256, 256, 0, stream>>>(edge_index, edge_attr, rowptr, fill, csr);

    // conversions + weight packing
    k_convx<<<(N_NODES * DIN / 4 + 255) / 256, 256, 0, stream>>>(x, xb);
    k_pack<<<928, 256, 0, stream>>>(Wk, Wq, Wv, Ws, W_in, W_out, Bq, Bin, Bout);

    k_in_mfma<<<RT, 256, 0, stream>>>(xb, Bin, b_in, hb);
    for (int l = 0; l < 3; ++l) {
        k_qkvs_mfma<<<2 * RT, 256, 0, stream>>>(hb, Bq + (size_t)l * 512 * 128,
                                                bk + l * H, bq + l * H, bv + l * H, b_gcn + l * H,
                                                ko, qv, agg);
        k_agg_ln<<<N_NODES / 4, 256, 0, stream>>>(rowptr, csr, ko, (const uint2*)qv, agg,
                                                  We + l * H, be + l * H,
                                                  gamma + l * H, beta + l * H, hb);
    }
    k_out_mfma<<<RT, 256, 0, stream>>>(hb, Bout, out);
}